// Round 6
// baseline (415.054 us; speedup 1.0000x reference)
//
#include <hip/hip_runtime.h>
#include <math.h>

#define NPTS   8192
#define BATCH  4
#define KNN    20
#define NKTOT  (NPTS*KNN)        // 163840 spatial positions per batch
#define EPS    1e-5f
#define FQC    64                // per-query SHARED queue cap (cluster-proof)

// windowed-KNN parameters. R5: WINW==gate window — the rank-44 lane-max gate
// over the FULL window is the tightest legal gate; completeness failures are
// caught by the verifier and repaired by the fallback.
#define WINW   2048              // sorted-x window width (both passes)
#define WITR   (WINW/4/128)      // 4 iterations of 128 candidates per wave
#define NBIN   1024
#define BIN_LO (-4.5f)
#define BIN_W  (9.0f/1024.0f)

typedef float v2f __attribute__((ext_vector_type(2)));

__device__ __forceinline__ float elu(float x) { return x > 0.0f ? x : expm1f(x); }
__device__ __forceinline__ float eluf(float x) { return x > 0.0f ? x : __expf(x) - 1.0f; }
__device__ __forceinline__ v2f splat2(float x) { v2f v; v.x = x; v.y = x; return v; }
__device__ __forceinline__ float rfl(float x) {
    return __uint_as_float(__builtin_amdgcn_readfirstlane(__float_as_uint(x)));
}

// monotone float <-> unsigned encoding for atomic max/min on floats
__device__ __forceinline__ unsigned fenc(float f) {
    unsigned b = __float_as_uint(f);
    return b ^ ((unsigned)(((int)b) >> 31) | 0x80000000u);
}
__device__ __forceinline__ float fdec(unsigned u) {
    unsigned b = (u & 0x80000000u) ? (u ^ 0x80000000u) : ~u;
    return __uint_as_float(b);
}

// x-bin assignment — MUST be the identical expression everywhere it is used
__device__ __forceinline__ int xbin(float x) {
    int bin = (int)floorf((x + 4.5f) * (1024.0f / 9.0f));
    return bin < 0 ? 0 : (bin > NBIN - 1 ? NBIN - 1 : bin);
}

// key packing: [score:32 | (8191-orig):13 | slot:13].  Descending sort order
// == (score desc, original-index asc) — exact lax.top_k tie-break — while the
// low 13 bits carry the SORTED slot we emit (downstream works in sorted domain).
__device__ __forceinline__ unsigned long long packkey(float s, int orig, int slot) {
    return ((unsigned long long)fenc(s) << 32)
         | (unsigned)(((NPTS - 1 - orig) << 13) | slot);
}

// ---------------------------------------------------------------------------
// K0: pack points into (x,y,z,-0.5*|p|^2), init accumulator workspace, AND
// build per-block x-histogram partials (each block covers 256 points of one
// batch; 32 blocks per batch).
// ---------------------------------------------------------------------------
__global__ __launch_bounds__(256) void prep_kernel(const float* __restrict__ points,
                                                   float4* __restrict__ pts4,
                                                   float* __restrict__ zeroreg,   // 18176 words
                                                   unsigned* __restrict__ minenc, // 5120 words
                                                   unsigned* __restrict__ fcnt,   // 8 words
                                                   int* __restrict__ Pcur_part)   // 128*1024
{
    __shared__ int lh[NBIN];
    const int t = blockIdx.x * 256 + threadIdx.x;     // 32768
    const int b = t >> 13, n = t & (NPTS - 1);
    for (int i = threadIdx.x; i < NBIN; i += 256) lh[i] = 0;
    const float* px = points + b * 3 * NPTS;
    float x = px[n], y = px[NPTS + n], z = px[2 * NPTS + n];
    pts4[t] = make_float4(x, y, z, -0.5f * (x * x + y * y + z * z));
    if (t < 18176) zeroreg[t] = 0.f;
    if (t < 5120)  minenc[t] = 0xFFFFFFFFu;
    if (t < 8)     fcnt[t] = 0u;   // [0..3]=fb counters, [4]=moments ctr, [5]=fused ctr
    __syncthreads();
    atomicAdd(&lh[xbin(x)], 1);
    __syncthreads();
    for (int i = threadIdx.x; i < NBIN; i += 256)
        Pcur_part[blockIdx.x * NBIN + i] = lh[i];
}

// ---------------------------------------------------------------------------
// K0c: scatter into bin-ordered layout. R5: each block redundantly rebuilds
// the global prefix from the 32 per-block partials (removes the serialized
// 4-block scan kernel) and derives exact slots as
//   global_excl_prefix[bin] + count-in-earlier-blocks[bin] + local rank
// — no global atomics. Within-bin order nondeterministic only within a block
// (irrelevant: analytic bin-edge bounds; network is a set-op in n).
// ---------------------------------------------------------------------------
__global__ __launch_bounds__(256) void scatter_kernel(const float4* __restrict__ pts4,
                                                      const int* __restrict__ Pcur_part,
                                                      float4* __restrict__ psort,
                                                      int* __restrict__ sidx,
                                                      int* __restrict__ binof)
{
    __shared__ int boff[NBIN];     // per-bin slot base for THIS block
    __shared__ int brank[NBIN];    // within-block rank counters
    __shared__ int wsum[256];
    const int jb = blockIdx.x & 31;       // block index within batch
    const int b  = blockIdx.x >> 5;
    const int tt = threadIdx.x;
    const int t0 = tt * 4;                // this thread owns bins [t0, t0+4)

    int tot0 = 0, tot1 = 0, tot2 = 0, tot3 = 0;
    int pre0 = 0, pre1 = 0, pre2 = 0, pre3 = 0;
    for (int p = 0; p < 32; ++p) {
        const int4 c = *(const int4*)&Pcur_part[(b * 32 + p) * NBIN + t0];
        tot0 += c.x; tot1 += c.y; tot2 += c.z; tot3 += c.w;
        if (p < jb) { pre0 += c.x; pre1 += c.y; pre2 += c.z; pre3 += c.w; }
    }
    const int tsum = tot0 + tot1 + tot2 + tot3;
    wsum[tt] = tsum;
    __syncthreads();
    for (int off = 1; off < 256; off <<= 1) {          // Hillis-Steele incl scan
        int a = (tt >= off) ? wsum[tt - off] : 0;
        __syncthreads();
        wsum[tt] += a;
        __syncthreads();
    }
    int run = wsum[tt] - tsum;            // exclusive batch-prefix at bin t0
    boff[t0 + 0] = run + pre0; run += tot0;
    boff[t0 + 1] = run + pre1; run += tot1;
    boff[t0 + 2] = run + pre2; run += tot2;
    boff[t0 + 3] = run + pre3;
    for (int i = tt; i < NBIN; i += 256) brank[i] = 0;
    __syncthreads();

    const int n = jb * 256 + tt;
    float4 p = pts4[b * NPTS + n];
    int bin = xbin(p.x);
    int slot = boff[bin] + atomicAdd(&brank[bin], 1);
    psort[b * NPTS + slot] = p;
    sidx [b * NPTS + slot] = n;
    binof[b * NPTS + slot] = bin;
}

// ---------------------------------------------------------------------------
// K1: windowed exact KNN in the SORTED domain. Octet = 8 consecutive sorted
// positions; ONE WINW=2048 window serves both passes. Pass 1: per-lane max
// (lane-group = 32 points; rank-44 of the 64 combined lane-maxima is a
// provable LB on the window's 20th-best score — at most 19 lane-groups can
// contain a top-19 point, so >=45 lane-maxes <= s20). Pass 2: gated append
// into ONE shared cap-64 queue per query. Overflow / short queue / window-
// incompleteness (d20^2 vs analytic bin-edge bounds) -> fallback worklist.
// Half-wave chunk interleave keeps loads 1KB-contiguous. grid: 4096 x 256.
// ---------------------------------------------------------------------------
__global__ __launch_bounds__(256, 8) void knn_win_kernel(
    const float4* __restrict__ psort, const int* __restrict__ sidx,
    const int* __restrict__ binof, int* __restrict__ idx_out,
    unsigned* __restrict__ fcnt, int* __restrict__ flist)
{
    __shared__ unsigned long long queue[8][FQC];   // per-QUERY shared, 4 KB
    __shared__ float smaxs[4][8][64];              // 8 KB lane-maxima shares
    __shared__ float gates[8];
    __shared__ int qcnt[8];

    const int tid  = threadIdx.x;
    const int lane = tid & 63;
    const int wv   = tid >> 6;
    const int b    = blockIdx.x >> 10;    // 1024 blocks per batch
    const int oct  = blockIdx.x & 1023;
    const int q0s  = oct * 8;             // sorted-position base of this octet
    const float4* psb = psort + b * NPTS;
    const int*    six = sidx  + b * NPTS;
    const int*    bob = binof + b * NPTS;

    int s = q0s + 4 - WINW / 2;           // window start (sorted position)
    if (s < 0) s = 0;
    if (s > NPTS - WINW) s = NPTS - WINW;

    if (tid < 8) qcnt[tid] = 0;

    float qx[8], qy[8], qz[8], q2[8];
    v2f smax2[8];
#pragma unroll
    for (int q = 0; q < 8; ++q) {
        float4 qp = psb[q0s + q];
        qx[q] = rfl(qp.x); qy[q] = rfl(qp.y); qz[q] = rfl(qp.z);
        q2[q] = rfl(-(qp.w + qp.w));      // |q|^2
        smax2[q] = splat2(-INFINITY);
    }

    // half-wave-chunk interleave: chunk = 64 points; chunk c -> wave c&3;
    // iter t covers local chunks 2t (lanes<32) and 2t+1 (lanes>=32).
    const int lbase = s + (((lane >> 5) * 4 + wv) << 6) + ((lane & 31) << 1);

    // ---- pass 1: per-lane max over this wave's share of the window ----
#pragma unroll
    for (int t = 0; t < WITR; ++t) {
        float4 p0 = psb[lbase + t * 512];
        float4 p1 = psb[lbase + t * 512 + 1];
        v2f px = { p0.x, p1.x }, py = { p0.y, p1.y };
        v2f pz = { p0.z, p1.z }, pw = { p0.w, p1.w };
#pragma unroll
        for (int q = 0; q < 8; ++q) {
            v2f sv = __builtin_elementwise_fma(splat2(qx[q]), px,
                     __builtin_elementwise_fma(splat2(qy[q]), py,
                     __builtin_elementwise_fma(splat2(qz[q]), pz, pw)));
            smax2[q] = __builtin_elementwise_max(smax2[q], sv);
        }
    }
#pragma unroll
    for (int q = 0; q < 8; ++q) smaxs[wv][q][lane] = fmaxf(smax2[q].x, smax2[q].y);
    __syncthreads();

    // ---- gate: combine 4 wave-shares elementwise; each wave sorts 2 q's ----
#pragma unroll
    for (int qq = 0; qq < 2; ++qq) {
        const int q = wv * 2 + qq;
        float v = fmaxf(fmaxf(smaxs[0][q][lane], smaxs[1][q][lane]),
                        fmaxf(smaxs[2][q][lane], smaxs[3][q][lane]));
#pragma unroll
        for (int k = 2; k <= 64; k <<= 1)
#pragma unroll
            for (int j = k >> 1; j >= 1; j >>= 1) {
                float o = __shfl_xor(v, j);
                bool up = ((lane & k) == 0);
                bool keepmin = (((lane & j) == 0) == up);
                v = keepmin ? fminf(v, o) : fmaxf(v, o);
            }
        float m = __shfl(v, 44);          // provable LB on window 20th-best
        if (lane == 0) gates[q] = m - 1e-4f - 1e-5f * fabsf(m);
    }
    __syncthreads();
    float sgate[8];
#pragma unroll
    for (int q = 0; q < 8; ++q) sgate[q] = gates[q];

    // ---- pass 2: gated append into the SHARED per-query queues ----
#pragma unroll
    for (int t = 0; t < WITR; ++t) {
        const int jb = lbase + t * 512;
        float4 p0 = psb[jb];
        float4 p1 = psb[jb + 1];
        v2f px = { p0.x, p1.x }, py = { p0.y, p1.y };
        v2f pz = { p0.z, p1.z }, pw = { p0.w, p1.w };
#pragma unroll
        for (int q = 0; q < 8; ++q) {
            v2f sv = __builtin_elementwise_fma(splat2(qx[q]), px,
                     __builtin_elementwise_fma(splat2(qy[q]), py,
                     __builtin_elementwise_fma(splat2(qz[q]), pz, pw)));
            if (fmaxf(sv.x, sv.y) >= sgate[q]) {     // common case: wave skips
#pragma unroll
                for (int h = 0; h < 2; ++h) {
                    float svh = h ? sv.y : sv.x;
                    if (svh >= sgate[q]) {
                        int slot = atomicAdd(&qcnt[q], 1);
                        if (slot < FQC)
                            queue[q][slot] = packkey(svh, six[jb + h], jb + h);
                    }
                }
            }
        }
    }
    __syncthreads();

    // ---- analytic window bounds from bin edges ----
    float xLe = (s == 0) ? -3.0e38f
                         : (BIN_LO + (float)(bob[s] + 1) * BIN_W);        // e_hi(bin at s)
    float xRe = (s == NPTS - WINW) ? 3.0e38f
                         : (BIN_LO + (float)bob[s + WINW] * BIN_W);       // e_lo(bin at s+WINW)

    // ---- final: sort each query's shared queue, emit, verify ----
#pragma unroll
    for (int qq = 0; qq < 2; ++qq) {
        const int q = wv * 2 + qq;
        const int cr = qcnt[q];
        const bool ovf = (cr > FQC);
        const int c = cr < FQC ? cr : FQC;
        unsigned long long key = (lane < c) ? queue[q][lane] : 0ull;
#pragma unroll
        for (int k = 2; k <= 64; k <<= 1)
#pragma unroll
            for (int j = k >> 1; j >= 1; j >>= 1) {
                unsigned long long o = __shfl_xor(key, j);
                bool up = ((lane & k) == 0);
                bool keepmax = (((lane & j) == 0) == up);
                bool omax = o > key;
                key = (keepmax == omax) ? o : key;
            }
        if (lane < KNN)
            idx_out[(b * KNN + lane) * NPTS + (q0s + q)] =   // [b][k][n] sorted col
                (int)(unsigned)(key & 0x1FFFu);              // SORTED slot

        // verify: queue complete AND true 20-NN cannot live outside window
        unsigned long long k19 = __shfl(key, 19);
        float s20 = fdec((unsigned)(k19 >> 32));
        float d20 = fmaxf(q2[q] - 2.0f * s20, 0.0f);    // d20^2
        float mg  = 1e-3f + 1e-3f * d20;
        float dL  = qx[q] - xLe;
        float dR  = xRe - qx[q];
        bool ok = !ovf && (c >= KNN) && dL > 0.0f && dR > 0.0f
                  && (d20 + mg < dL * dL) && (d20 + mg < dR * dR);
        if (!ok && lane == 0) {
            unsigned fs = atomicAdd(&fcnt[b], 1u);
            if (fs < 8192u) flist[b * 8192 + fs] = q0s + q;  // sorted slot
        }
    }
}

// ---------------------------------------------------------------------------
// K1b: exact full-scan fallback, 2 queries per block-task, SHARED cap-64
// queue per query (cluster-proof — R2 lesson). grid: 4096 x 256.
// ---------------------------------------------------------------------------
__global__ __launch_bounds__(256, 8) void knn_fb_kernel(const float4* __restrict__ psort,
                                                        const int* __restrict__ sidx,
                                                        int* __restrict__ idx_out,
                                                        const unsigned* __restrict__ fcnt,
                                                        const int* __restrict__ flist)
{
    __shared__ unsigned long long queue[2][FQC];   // per-QUERY shared queues, 1 KB
    __shared__ float smaxs[4][2][64];
    __shared__ float gates[2];
    __shared__ int qcnt[2];

    const int tid  = threadIdx.x;
    const int lane = tid & 63;
    const int wv   = tid >> 6;
    const int bb   = blockIdx.x & 3;
    unsigned cnt = fcnt[bb];
    if (cnt > 8192u) cnt = 8192u;
    if (cnt == 0u) return;
    const float4* pb = psort + bb * NPTS;
    const int* six = sidx + bb * NPTS;
    const int* fl = flist + bb * 8192;
    const int cbase = wv * (NPTS / 4);
    const int tstep = gridDim.x >> 2;

    for (int task = blockIdx.x >> 2; task * 2 < (int)cnt; task += tstep) {
        int qs[2];
        float qx[2], qy[2], qz[2];
        v2f smax2[2];
        if (tid < 2) qcnt[tid] = 0;
#pragma unroll
        for (int q = 0; q < 2; ++q) {
            int e = task * 2 + q;
            if (e >= (int)cnt) e = (int)cnt - 1;      // pad with dup (benign)
            qs[q] = __builtin_amdgcn_readfirstlane(fl[e]);
            float4 qp = pb[qs[q]];
            qx[q] = rfl(qp.x); qy[q] = rfl(qp.y); qz[q] = rfl(qp.z);
            smax2[q] = splat2(-INFINITY);
        }

#pragma unroll 4
        for (int t = 0; t < NPTS / 4 / 128; ++t) {
            float4 p0 = pb[cbase + t * 128 + 2 * lane];
            float4 p1 = pb[cbase + t * 128 + 2 * lane + 1];
            v2f px = { p0.x, p1.x }, py = { p0.y, p1.y };
            v2f pz = { p0.z, p1.z }, pw = { p0.w, p1.w };
#pragma unroll
            for (int q = 0; q < 2; ++q) {
                v2f sv = __builtin_elementwise_fma(splat2(qx[q]), px,
                         __builtin_elementwise_fma(splat2(qy[q]), py,
                         __builtin_elementwise_fma(splat2(qz[q]), pz, pw)));
                smax2[q] = __builtin_elementwise_max(smax2[q], sv);
            }
        }
#pragma unroll
        for (int q = 0; q < 2; ++q) smaxs[wv][q][lane] = fmaxf(smax2[q].x, smax2[q].y);
        __syncthreads();

        if (wv < 2) {
            const int q = wv;
            float v = fmaxf(fmaxf(smaxs[0][q][lane], smaxs[1][q][lane]),
                            fmaxf(smaxs[2][q][lane], smaxs[3][q][lane]));
#pragma unroll
            for (int k = 2; k <= 64; k <<= 1)
#pragma unroll
                for (int j = k >> 1; j >= 1; j >>= 1) {
                    float o = __shfl_xor(v, j);
                    bool up = ((lane & k) == 0);
                    bool keepmin = (((lane & j) == 0) == up);
                    v = keepmin ? fminf(v, o) : fmaxf(v, o);
                }
            float m = __shfl(v, 44);
            if (lane == 0) gates[q] = m - 1e-4f - 1e-5f * fabsf(m);
        }
        __syncthreads();
        float sg0 = gates[0], sg1 = gates[1];

        for (int t = 0; t < NPTS / 4 / 128; ++t) {
            const int jb = cbase + t * 128 + 2 * lane;
            float4 p0 = pb[jb];
            float4 p1 = pb[jb + 1];
            v2f px = { p0.x, p1.x }, py = { p0.y, p1.y };
            v2f pz = { p0.z, p1.z }, pw = { p0.w, p1.w };
#pragma unroll
            for (int q = 0; q < 2; ++q) {
                float sg = q ? sg1 : sg0;
                v2f sv = __builtin_elementwise_fma(splat2(qx[q]), px,
                         __builtin_elementwise_fma(splat2(qy[q]), py,
                         __builtin_elementwise_fma(splat2(qz[q]), pz, pw)));
                if (fmaxf(sv.x, sv.y) >= sg) {
#pragma unroll
                    for (int h = 0; h < 2; ++h) {
                        float svh = h ? sv.y : sv.x;
                        if (svh >= sg) {
                            int slot = atomicAdd(&qcnt[q], 1);
                            if (slot < FQC)
                                queue[q][slot] = packkey(svh, six[jb + h], jb + h);
                        }
                    }
                }
            }
        }
        __syncthreads();

        if (wv < 2) {
            const int q = wv;
            int c = qcnt[q]; c = c < FQC ? c : FQC;
            unsigned long long key = (lane < c) ? queue[q][lane] : 0ull;
#pragma unroll
            for (int k = 2; k <= 64; k <<= 1)
#pragma unroll
                for (int j = k >> 1; j >= 1; j >>= 1) {
                    unsigned long long o = __shfl_xor(key, j);
                    bool up = ((lane & k) == 0);
                    bool keepmax = (((lane & j) == 0) == up);
                    bool omax = o > key;
                    key = (keepmax == omax) ? o : key;
                }
            if (lane < KNN)
                idx_out[(bb * KNN + lane) * NPTS + qs[q]] =
                    (int)(unsigned)(key & 0x1FFFu);
        }
        __syncthreads();   // protect LDS reuse by next task
    }
}

// ---------------------------------------------------------------------------
// K2(+K3 fused): x0 moments — SORTED domain. R5: the LAST block to finish
// (device-scope atomic counter + release/acquire threadfence — partials are
// atomicAdd'ed, so coherent) runs the old finalize1 body, removing a
// serialized 1-block launch. grid: 320 x 256.
// ---------------------------------------------------------------------------
__global__ __launch_bounds__(256) void moments_x_kernel(const float4* __restrict__ psort,
                                                        const int* __restrict__ idx,
                                                        float* __restrict__ sums1p,
                                                        const float* __restrict__ w1,
                                                        const float* __restrict__ b1,
                                                        const float* __restrict__ g1,
                                                        const float* __restrict__ beta1,
                                                        float* __restrict__ w1f,
                                                        unsigned* __restrict__ ctr)
{
    const int b  = blockIdx.x / 80;
    const int r0 = (blockIdx.x - b * 80) * 2048;
    const float4* pb = psort + b * NPTS;
    const int* ib = idx + b * NKTOT;

    float v[27];
#pragma unroll
    for (int i = 0; i < 27; ++i) v[i] = 0.f;

    for (int e = 0; e < 8; ++e) {
        const int id = r0 + e * 256 + threadIdx.x;   // [k][n] linear, coalesced
        const int n = id & (NPTS - 1);
        const int j = ib[id];
        float4 c4 = pb[n];
        float4 e4 = pb[j];
        float x[6] = { c4.x, c4.y, c4.z, e4.x - c4.x, e4.y - c4.y, e4.z - c4.z };
        int p = 6;
#pragma unroll
        for (int d = 0; d < 6; ++d) {
            v[d] += x[d];
#pragma unroll
            for (int ee = d; ee < 6; ++ee) v[p++] += x[d] * x[ee];
        }
    }
#pragma unroll
    for (int i = 0; i < 27; ++i)
        for (int o = 32; o > 0; o >>= 1) v[i] += __shfl_xor(v[i], o);

    __shared__ float red[4][27];
    const int lane = threadIdx.x & 63, w = threadIdx.x >> 6;
    if (lane == 0)
#pragma unroll
        for (int i = 0; i < 27; ++i) red[w][i] = v[i];
    __syncthreads();
    if (threadIdx.x < 27) {
        float acc = red[0][threadIdx.x] + red[1][threadIdx.x] + red[2][threadIdx.x] + red[3][threadIdx.x];
        int slot = blockIdx.x & 63;
        atomicAdd(&sums1p[(slot * BATCH + b) * 27 + threadIdx.x], acc);
    }

    // ---- last-block-done: run finalize1 ----
    __threadfence();
    __syncthreads();
    __shared__ int lastm;
    if (threadIdx.x == 0) lastm = (atomicAdd(ctr, 1u) == 319u) ? 1 : 0;
    __syncthreads();
    if (!lastm) return;
    __threadfence();   // acquire: all partials visible

    __shared__ float S[BATCH][27];
    const int t = threadIdx.x;
    if (t < 108) {
        int bb = t / 27, i = t % 27;
        float acc = 0.f;
        for (int s = 0; s < 64; ++s) acc += sums1p[(s * BATCH + bb) * 27 + i];
        S[bb][i] = acc;
    }
    __syncthreads();
    if (t < 128) {
        const int bb = t >> 5, c = t & 31;
        const float invS = 1.0f / (float)NKTOT;
        float Ex[6], M[6][6];
#pragma unroll
        for (int d = 0; d < 6; ++d) Ex[d] = S[bb][d] * invS;
        int p = 6;
#pragma unroll
        for (int d = 0; d < 6; ++d)
#pragma unroll
            for (int e = d; e < 6; ++e) { float vv = S[bb][p++] * invS; M[d][e] = vv; M[e][d] = vv; }
        const int g = c >> 2;
        float msum = 0.f, qsum = 0.f;
        for (int cc = g * 4; cc < g * 4 + 4; ++cc) {
            float wv[6];
#pragma unroll
            for (int d = 0; d < 6; ++d) wv[d] = w1[cc * 6 + d];
            float dotEx = 0.f;
#pragma unroll
            for (int d = 0; d < 6; ++d) dotEx += wv[d] * Ex[d];
            float Ey = dotEx + b1[cc];
            float Ey2 = 0.f;
#pragma unroll
            for (int d = 0; d < 6; ++d)
#pragma unroll
                for (int e = 0; e < 6; ++e) Ey2 += wv[d] * wv[e] * M[d][e];
            Ey2 += 2.0f * b1[cc] * dotEx + b1[cc] * b1[cc];
            msum += Ey; qsum += Ey2;
        }
        float m = msum * 0.25f;
        float var = qsum * 0.25f - m * m;
        float inv = rsqrtf(var + EPS);
        float sca = g1[c] * inv;
        float tt2 = sca * (b1[c] - m) + beta1[c];
        float* o = w1f + (bb * 32 + c) * 8;
#pragma unroll
        for (int d = 0; d < 6; ++d) o[d] = sca * w1[c * 6 + d];
        o[6] = tt2; o[7] = 0.f;
    }
}

// ---------------------------------------------------------------------------
// K4(+K5 fused): fused main pass (SORTED domain). R5: last block runs the old
// build_m1 body (maxenc/minenc/sums2p are all atomic-written -> coherent
// after fence), removing a serialized 20-block launch. grid: 1280 x 256.
// ---------------------------------------------------------------------------
__global__ __launch_bounds__(256, 3) void fused_main_kernel(
    const float4* __restrict__ psort, const int* __restrict__ idxb,
    const float* __restrict__ w1f, const float* __restrict__ w2, const float* __restrict__ b2,
    float* __restrict__ sums2p, unsigned int* __restrict__ maxenc, unsigned int* __restrict__ minenc,
    const float* __restrict__ gamma2, const float* __restrict__ beta2,
    float* __restrict__ m1, unsigned* __restrict__ ctr)
{
    __shared__ __align__(16) float w2t[32 * 64];    // W2^T: [k][c]   8 KB
    __shared__ __align__(16) float z1s[32 * 256];   // z1:   [k][n]  32 KB
    __shared__ __align__(16) float4 w1s4[64];       // folded W1 [32][8]
    __shared__ float b2s[64];
    __shared__ float redmx[256], redmn[256], sqred[64];

    const int t   = threadIdx.x;
    const int blk = blockIdx.x;
    const int nc  = blk & 15;
    const int k   = (blk >> 4) % 20;
    const int b   = blk / 320;          // 320 blocks per batch (16 nc * 20 k)

    for (int i = t; i < 512; i += 256) {
        float4 v = ((const float4*)w2)[i];
        int c = i >> 3, kq = (i & 7) * 4;
        w2t[(kq + 0) * 64 + c] = v.x; w2t[(kq + 1) * 64 + c] = v.y;
        w2t[(kq + 2) * 64 + c] = v.z; w2t[(kq + 3) * 64 + c] = v.w;
    }
    if (t < 64) { w1s4[t] = ((const float4*)w1f)[b * 64 + t]; b2s[t] = b2[t]; }

    const int wvi = t >> 6;
    const int cg8 = t & 7;            // channel octet == GN group (GEMM)
    const int n0  = (t >> 3) * 8;     // n-group base 0..248 (GEMM)
    const int c0  = cg8 * 8;
    const float4* pb = psort + b * NPTS;
    const int nbase = nc * 512;
    const int* idxrow = idxb + (b * KNN + k) * NPTS;   // [b][k][n]: coalesced

    float mx[8], mn[8];
#pragma unroll
    for (int ci = 0; ci < 8; ++ci) { mx[ci] = -INFINITY; mn[ci] = INFINITY; }
    float gs = 0.f, gq = 0.f;

    for (int ph = 0; ph < 2; ++ph) {
        // ---- fill z1[32][256]: thread owns n = nbase+ph*256+t, all 32 ch ----
        const int n = nbase + ph * 256 + t;
        const int j = idxrow[n];
        float4 c4 = pb[n];
        float4 e4 = pb[j];
        float x0[6] = { c4.x, c4.y, c4.z, e4.x - c4.x, e4.y - c4.y, e4.z - c4.z };

        __syncthreads();   // staging done (ph=0) / previous GEMM reads done
#pragma unroll
        for (int c = 0; c < 32; ++c) {
            float4 wA = w1s4[c * 2 + 0];
            float4 wB = w1s4[c * 2 + 1];
            float z = wB.z;
            z = fmaf(wA.x, x0[0], z); z = fmaf(wA.y, x0[1], z); z = fmaf(wA.z, x0[2], z);
            z = fmaf(wA.w, x0[3], z); z = fmaf(wB.x, x0[4], z); z = fmaf(wB.y, x0[5], z);
            z1s[c * 256 + t] = eluf(z);
        }
        __syncthreads();

        // ---- GEMM: 8c x 8n per thread, 4 b128 per 64 FMA ----
        float acc[8][8];
#pragma unroll
        for (int ci = 0; ci < 8; ++ci) {
            float bb = b2s[c0 + ci];
#pragma unroll
            for (int pj = 0; pj < 8; ++pj) acc[ci][pj] = bb;
        }
#pragma unroll
        for (int kk = 0; kk < 32; ++kk) {
            float4 a0 = *(const float4*)&w2t[kk * 64 + c0];
            float4 a1 = *(const float4*)&w2t[kk * 64 + c0 + 4];
            float4 z0 = *(const float4*)&z1s[kk * 256 + n0];
            float4 z1v = *(const float4*)&z1s[kk * 256 + n0 + 4];
            float avv[8] = { a0.x, a0.y, a0.z, a0.w, a1.x, a1.y, a1.z, a1.w };
            float zvv[8] = { z0.x, z0.y, z0.z, z0.w, z1v.x, z1v.y, z1v.z, z1v.w };
#pragma unroll
            for (int ci = 0; ci < 8; ++ci)
#pragma unroll
                for (int pj = 0; pj < 8; ++pj) acc[ci][pj] = fmaf(avv[ci], zvv[pj], acc[ci][pj]);
        }
#pragma unroll
        for (int ci = 0; ci < 8; ++ci)
#pragma unroll
            for (int pj = 0; pj < 8; ++pj) {
                float v = acc[ci][pj];
                gs += v; gq = fmaf(v, v, gq);
                mx[ci] = fmaxf(mx[ci], v); mn[ci] = fminf(mn[ci], v);
            }
    }

    // reduce over the 8 n-groups within this wave (lane bits 3,4,5)
#pragma unroll
    for (int m = 8; m <= 32; m <<= 1) {
#pragma unroll
        for (int ci = 0; ci < 8; ++ci) {
            mx[ci] = fmaxf(mx[ci], __shfl_xor(mx[ci], m));
            mn[ci] = fminf(mn[ci], __shfl_xor(mn[ci], m));
        }
        gs += __shfl_xor(gs, m);
        gq += __shfl_xor(gq, m);
    }
    if ((t & 63) < 8) {
        const int l = t & 7;
#pragma unroll
        for (int ci = 0; ci < 8; ++ci) {
            redmx[wvi * 64 + l * 8 + ci] = mx[ci];
            redmn[wvi * 64 + l * 8 + ci] = mn[ci];
        }
        sqred[(wvi * 8 + l) * 2 + 0] = gs;
        sqred[(wvi * 8 + l) * 2 + 1] = gq;
    }
    __syncthreads();
    if (t < 64) {
        float m = fmaxf(fmaxf(redmx[t], redmx[64 + t]), fmaxf(redmx[128 + t], redmx[192 + t]));
        atomicMax(&maxenc[(b * 64 + t) * KNN + k], fenc(m));
    } else if (t < 128) {
        int c = t - 64;
        float m = fminf(fminf(redmn[c], redmn[64 + c]), fminf(redmn[128 + c], redmn[192 + c]));
        atomicMin(&minenc[(b * 64 + c) * KNN + k], fenc(m));
    } else if (t < 144) {
        int i2 = t - 128, g = i2 >> 1, w = i2 & 1;
        float v = 0.f;
#pragma unroll
        for (int wv2 = 0; wv2 < 4; ++wv2)
            v += sqred[(wv2 * 8 + g) * 2 + w];
        int slot = blk & 63;
        atomicAdd(&sums2p[((slot * BATCH + b) * 8 + g) * 2 + w], v);
    }

    // ---- last-block-done: run build_m1 ----
    __threadfence();
    __syncthreads();
    __shared__ int lastf;
    if (t == 0) lastf = (atomicAdd(ctr, 1u) == 1279u) ? 1 : 0;
    __syncthreads();
    if (!lastf) return;
    __threadfence();   // acquire: all atomics visible

    __shared__ float smv[4][8][2];
    if (t < 64) {
        int bb = t >> 4, g = (t >> 1) & 7, w = t & 1;
        float a = 0.f;
        for (int sl = 0; sl < 64; ++sl)
            a += sums2p[((sl * BATCH + bb) * 8 + g) * 2 + w];
        smv[bb][g][w] = a;
    }
    __syncthreads();
    const float cnt = 8.0f * (float)NKTOT;
    for (int i = t; i < BATCH * 64 * KNN; i += 256) {
        const int bb = i / 1280;
        const int r = i - bb * 1280;
        const int c = r / 20;
        const int g = c >> 3;
        float m = smv[bb][g][0] / cnt;
        float var = smv[bb][g][1] / cnt - m * m;
        float inv = rsqrtf(var + EPS);
        float sc = gamma2[c] * inv;
        float tt2 = beta2[c] - sc * m;
        float y = (sc >= 0.f) ? fdec(maxenc[i]) : fdec(minenc[i]);
        m1[i] = elu(sc * y + tt2);
    }
}

// ---------------------------------------------------------------------------
// K6/K8: pointwise conv (CIN -> COUT over K=20) + raw output + GN stat partials
// ---------------------------------------------------------------------------
template <int CIN, int SLOTS>
__global__ void p2_gemm_kernel(const float* __restrict__ zin, const float* __restrict__ w,
                               const float* __restrict__ bias, float* __restrict__ yout,
                               float* __restrict__ sumsp, int chans_per_group)
{
    const int t = blockIdx.x * 256 + threadIdx.x;
    const int per_b = (gridDim.x * 256) / BATCH;
    const int b = t / per_b;
    const int r = t - b * per_b;
    const int o = r / 20;
    const int k = r - o * 20;
    const float* zb = zin + b * CIN * 20;
    const float* wrow = w + o * CIN;
    float acc = bias[o];
    for (int c = 0; c < CIN; c += 4) {
        float4 wv = *(const float4*)&wrow[c];
        acc += wv.x * zb[(c + 0) * 20 + k] + wv.y * zb[(c + 1) * 20 + k]
             + wv.z * zb[(c + 2) * 20 + k] + wv.w * zb[(c + 3) * 20 + k];
    }
    yout[t] = acc;

    __shared__ float ls[16];
    if (threadIdx.x < 16) ls[threadIdx.x] = 0.f;
    __syncthreads();
    const int g = o / chans_per_group;
    atomicAdd(&ls[g * 2 + 0], acc);
    atomicAdd(&ls[g * 2 + 1], acc * acc);
    __syncthreads();
    if (threadIdx.x < 16) {
        int slot = blockIdx.x & (SLOTS - 1);
        atomicAdd(&sumsp[(slot * BATCH + b) * 16 + threadIdx.x], ls[threadIdx.x]);
    }
}

// K7/K9: apply GN affine + ELU using partial sums
template <int SLOTS>
__global__ void p2_finalize_kernel(const float* __restrict__ y, const float* __restrict__ sumsp,
                                   const float* __restrict__ gamma, const float* __restrict__ beta,
                                   float* __restrict__ z, int chans_per_group, float cnt)
{
    const int t = blockIdx.x * 256 + threadIdx.x;
    const int per_b = (gridDim.x * 256) / BATCH;
    const int b = t / per_b;
    const int r = t - b * per_b;
    const int o = r / 20;
    const int g = o / chans_per_group;
    float s = 0.f, q = 0.f;
    for (int sl = 0; sl < SLOTS; ++sl) {
        s += sumsp[(sl * BATCH + b) * 16 + g * 2 + 0];
        q += sumsp[(sl * BATCH + b) * 16 + g * 2 + 1];
    }
    float m = s / cnt;
    float var = q / cnt - m * m;
    float inv = rsqrtf(var + EPS);
    float v = gamma[o] * inv * (y[t] - m) + beta[o];
    z[t] = elu(v);
}

// ---------------------------------------------------------------------------
extern "C" void kernel_launch(void* const* d_in, const int* in_sizes, int n_in,
                              void* d_out, int out_size, void* d_ws, size_t ws_size,
                              hipStream_t stream)
{
    const float* points  = (const float*)d_in[0];
    const float* p1_w0   = (const float*)d_in[1];
    const float* p1_b0   = (const float*)d_in[2];
    const float* p1_g0   = (const float*)d_in[3];
    const float* p1_bt0  = (const float*)d_in[4];
    const float* p1_w1   = (const float*)d_in[5];
    const float* p1_b1   = (const float*)d_in[6];
    const float* p1_g1   = (const float*)d_in[7];
    const float* p1_bt1  = (const float*)d_in[8];
    const float* p2_w0   = (const float*)d_in[9];
    const float* p2_b0   = (const float*)d_in[10];
    const float* p2_g0   = (const float*)d_in[11];
    const float* p2_bt0  = (const float*)d_in[12];
    const float* p2_w1   = (const float*)d_in[13];
    const float* p2_b1   = (const float*)d_in[14];
    const float* p2_g1   = (const float*)d_in[15];
    const float* p2_bt1  = (const float*)d_in[16];
    float* out = (float*)d_out;

    float* ws = (float*)d_ws;
    int*      idx     = (int*)ws;                    // 655360  ([b][k][n], sorted cols)
    float*    sums1p  = ws + 655360;                 // 6912   (zeroed by prep)
    float*    sums2p  = sums1p + 6912;               // 4096   (zeroed by prep)
    float*    sumsAp  = sums2p + 4096;               // 1024   (zeroed by prep)
    float*    sumsBp  = sumsAp + 1024;               // 1024   (zeroed by prep)
    unsigned* maxenc  = (unsigned*)(sumsBp + 1024);  // 5120   (zeroed by prep)
    unsigned* minenc  = maxenc + 5120;               // 5120   (0xFF by prep)
    float*    w1f     = (float*)(minenc + 5120);     // 1024
    float*    m1      = w1f + 1024;                  // 5120
    float*    yp2a    = m1 + 5120;                   // 40960
    float*    zp2a    = yp2a + 40960;                // 40960
    float*    yp2b    = zp2a + 40960;                // 81920
    // pts4 (original order) aliases yp2a onward; live only until scatter.
    float4*   pts4    = (float4*)yp2a;
    // hist partials alias the idx region (consumed by scatter BEFORE knn writes idx)
    int*      Pcur_part = idx;                       // 131072 ints, transient
    // sorted-domain arrays (fresh space after yp2b; psort lives through fused_main)
    float*    psortf  = yp2b + 81920;                // 131072 (float4[4][8192])
    float4*   psort4  = (float4*)psortf;
    int*      sidx    = (int*)(psortf + 131072);     // 32768
    int*      binof   = sidx + 32768;                // 32768 (+64 pad)
    unsigned* fcnt8   = (unsigned*)(binof + 32768 + 64); // 8 (+56 pad)
    int*      flist   = (int*)(fcnt8 + 64);          // 32768 (4 x 8192 per-batch lists)

    // zero region = sums1p..maxenc contiguous: 6912+4096+1024+1024+5120 = 18176
    prep_kernel<<<128, 256, 0, stream>>>(points, pts4, sums1p, minenc, fcnt8, Pcur_part);
    scatter_kernel<<<128, 256, 0, stream>>>(pts4, Pcur_part, psort4, sidx, binof);
    knn_win_kernel<<<4096, 256, 0, stream>>>(psort4, sidx, binof, idx, fcnt8, flist);
    knn_fb_kernel<<<4096, 256, 0, stream>>>(psort4, sidx, idx, fcnt8, flist);
    moments_x_kernel<<<320, 256, 0, stream>>>(psort4, idx, sums1p,
                                              p1_w0, p1_b0, p1_g0, p1_bt0, w1f, fcnt8 + 4);
    // grid MUST be 1280 = 4 b * 20 k * 16 nc  (b = blk/320; larger grids give
    // b >= BATCH -> OOB idx reads -> memory fault, see R4 crash)
    fused_main_kernel<<<1280, 256, 0, stream>>>(psort4, idx, w1f, p1_w1, p1_b1,
                                                sums2p, maxenc, minenc,
                                                p1_g1, p1_bt1, m1, fcnt8 + 5);
    p2_gemm_kernel<64, 16><<<160, 256, 0, stream>>>(m1, p2_w0, p2_b0, yp2a, sumsAp, 64);
    p2_finalize_kernel<16><<<160, 256, 0, stream>>>(yp2a, sumsAp, p2_g0, p2_bt0, zp2a, 64, 1280.0f);
    p2_gemm_kernel<512, 16><<<320, 256, 0, stream>>>(zp2a, p2_w1, p2_b1, yp2b, sumsBp, 128);
    p2_finalize_kernel<16><<<320, 256, 0, stream>>>(yp2b, sumsBp, p2_g1, p2_bt1, out, 128, 2560.0f);
}

// Round 7
// 333.145 us; speedup vs baseline: 1.2459x; 1.2459x over previous
//
#include <hip/hip_runtime.h>
#include <math.h>

#define NPTS   8192
#define BATCH  4
#define KNN    20
#define NKTOT  (NPTS*KNN)        // 163840 spatial positions per batch
#define EPS    1e-5f
#define FQC    64                // per-query SHARED queue cap (cluster-proof)

// windowed-KNN parameters: WINW==gate window — the rank-44 lane-max gate over
// the FULL window is the tightest legal gate; completeness failures are
// caught by the verifier and repaired by the fallback.
#define WINW   2048              // sorted-x window width (both passes)
#define WITR   (WINW/4/128)      // 4 iterations of 128 candidates per wave
#define NBIN   1024
#define BIN_LO (-4.5f)
#define BIN_W  (9.0f/1024.0f)

typedef float v2f __attribute__((ext_vector_type(2)));

__device__ __forceinline__ float elu(float x) { return x > 0.0f ? x : expm1f(x); }
__device__ __forceinline__ float eluf(float x) { return x > 0.0f ? x : __expf(x) - 1.0f; }
__device__ __forceinline__ v2f splat2(float x) { v2f v; v.x = x; v.y = x; return v; }
__device__ __forceinline__ float rfl(float x) {
    return __uint_as_float(__builtin_amdgcn_readfirstlane(__float_as_uint(x)));
}

// monotone float <-> unsigned encoding for atomic max/min on floats
__device__ __forceinline__ unsigned fenc(float f) {
    unsigned b = __float_as_uint(f);
    return b ^ ((unsigned)(((int)b) >> 31) | 0x80000000u);
}
__device__ __forceinline__ float fdec(unsigned u) {
    unsigned b = (u & 0x80000000u) ? (u ^ 0x80000000u) : ~u;
    return __uint_as_float(b);
}

// x-bin assignment — MUST be the identical expression everywhere it is used
__device__ __forceinline__ int xbin(float x) {
    int bin = (int)floorf((x + 4.5f) * (1024.0f / 9.0f));
    return bin < 0 ? 0 : (bin > NBIN - 1 ? NBIN - 1 : bin);
}

// key packing: [score:32 | (8191-orig):13 | slot:13].  Descending sort order
// == (score desc, original-index asc) — exact lax.top_k tie-break — while the
// low 13 bits carry the SORTED slot we emit (downstream works in sorted domain).
__device__ __forceinline__ unsigned long long packkey(float s, int orig, int slot) {
    return ((unsigned long long)fenc(s) << 32)
         | (unsigned)(((NPTS - 1 - orig) << 13) | slot);
}

// ---------------------------------------------------------------------------
// K0: pack points into (x,y,z,-0.5*|p|^2), init accumulator workspace, AND
// build per-block x-histogram partials (each block covers 256 points of one
// batch; 32 blocks per batch).
// ---------------------------------------------------------------------------
__global__ __launch_bounds__(256) void prep_kernel(const float* __restrict__ points,
                                                   float4* __restrict__ pts4,
                                                   float* __restrict__ zeroreg,   // 18176 words
                                                   unsigned* __restrict__ minenc, // 5120 words
                                                   unsigned* __restrict__ fcnt,   // 8 words
                                                   int* __restrict__ Pcur_part)   // 128*1024
{
    __shared__ int lh[NBIN];
    const int t = blockIdx.x * 256 + threadIdx.x;     // 32768
    const int b = t >> 13, n = t & (NPTS - 1);
    for (int i = threadIdx.x; i < NBIN; i += 256) lh[i] = 0;
    const float* px = points + b * 3 * NPTS;
    float x = px[n], y = px[NPTS + n], z = px[2 * NPTS + n];
    pts4[t] = make_float4(x, y, z, -0.5f * (x * x + y * y + z * z));
    if (t < 18176) zeroreg[t] = 0.f;
    if (t < 5120)  minenc[t] = 0xFFFFFFFFu;
    if (t < 8)     fcnt[t] = 0u;   // [0..3]=fb counters, rest spare
    __syncthreads();
    atomicAdd(&lh[xbin(x)], 1);
    __syncthreads();
    for (int i = threadIdx.x; i < NBIN; i += 256)
        Pcur_part[blockIdx.x * NBIN + i] = lh[i];
}

// ---------------------------------------------------------------------------
// K0c: scatter into bin-ordered layout. Each block redundantly rebuilds the
// global prefix from the 32 per-block partials (no serialized scan kernel)
// and derives exact slots as
//   global_excl_prefix[bin] + count-in-earlier-blocks[bin] + local rank
// — no global atomics. Within-bin order nondeterministic only within a block
// (irrelevant: analytic bin-edge bounds; network is a set-op in n).
// ---------------------------------------------------------------------------
__global__ __launch_bounds__(256) void scatter_kernel(const float4* __restrict__ pts4,
                                                      const int* __restrict__ Pcur_part,
                                                      float4* __restrict__ psort,
                                                      int* __restrict__ sidx,
                                                      int* __restrict__ binof)
{
    __shared__ int boff[NBIN];     // per-bin slot base for THIS block
    __shared__ int brank[NBIN];    // within-block rank counters
    __shared__ int wsum[256];
    const int jb = blockIdx.x & 31;       // block index within batch
    const int b  = blockIdx.x >> 5;
    const int tt = threadIdx.x;
    const int t0 = tt * 4;                // this thread owns bins [t0, t0+4)

    int tot0 = 0, tot1 = 0, tot2 = 0, tot3 = 0;
    int pre0 = 0, pre1 = 0, pre2 = 0, pre3 = 0;
    for (int p = 0; p < 32; ++p) {
        const int4 c = *(const int4*)&Pcur_part[(b * 32 + p) * NBIN + t0];
        tot0 += c.x; tot1 += c.y; tot2 += c.z; tot3 += c.w;
        if (p < jb) { pre0 += c.x; pre1 += c.y; pre2 += c.z; pre3 += c.w; }
    }
    const int tsum = tot0 + tot1 + tot2 + tot3;
    wsum[tt] = tsum;
    __syncthreads();
    for (int off = 1; off < 256; off <<= 1) {          // Hillis-Steele incl scan
        int a = (tt >= off) ? wsum[tt - off] : 0;
        __syncthreads();
        wsum[tt] += a;
        __syncthreads();
    }
    int run = wsum[tt] - tsum;            // exclusive batch-prefix at bin t0
    boff[t0 + 0] = run + pre0; run += tot0;
    boff[t0 + 1] = run + pre1; run += tot1;
    boff[t0 + 2] = run + pre2; run += tot2;
    boff[t0 + 3] = run + pre3;
    for (int i = tt; i < NBIN; i += 256) brank[i] = 0;
    __syncthreads();

    const int n = jb * 256 + tt;
    float4 p = pts4[b * NPTS + n];
    int bin = xbin(p.x);
    int slot = boff[bin] + atomicAdd(&brank[bin], 1);
    psort[b * NPTS + slot] = p;
    sidx [b * NPTS + slot] = n;
    binof[b * NPTS + slot] = bin;
}

// ---------------------------------------------------------------------------
// K1: windowed exact KNN in the SORTED domain. Octet = 8 consecutive sorted
// positions; ONE WINW=2048 window serves both passes. Pass 1: per-lane max
// (rank-44 of the 64 combined lane-maxima is a provable LB on the window's
// 20th-best score). Pass 2: gated append into ONE shared cap-64 queue per
// query. Overflow / short queue / window-incompleteness (d20^2 vs analytic
// bin-edge bounds) -> fallback worklist. Half-wave chunk interleave keeps
// loads 1KB-contiguous. grid: 4096 x 256.
// ---------------------------------------------------------------------------
__global__ __launch_bounds__(256, 8) void knn_win_kernel(
    const float4* __restrict__ psort, const int* __restrict__ sidx,
    const int* __restrict__ binof, int* __restrict__ idx_out,
    unsigned* __restrict__ fcnt, int* __restrict__ flist)
{
    __shared__ unsigned long long queue[8][FQC];   // per-QUERY shared, 4 KB
    __shared__ float smaxs[4][8][64];              // 8 KB lane-maxima shares
    __shared__ float gates[8];
    __shared__ int qcnt[8];

    const int tid  = threadIdx.x;
    const int lane = tid & 63;
    const int wv   = tid >> 6;
    const int b    = blockIdx.x >> 10;    // 1024 blocks per batch
    const int oct  = blockIdx.x & 1023;
    const int q0s  = oct * 8;             // sorted-position base of this octet
    const float4* psb = psort + b * NPTS;
    const int*    six = sidx  + b * NPTS;
    const int*    bob = binof + b * NPTS;

    int s = q0s + 4 - WINW / 2;           // window start (sorted position)
    if (s < 0) s = 0;
    if (s > NPTS - WINW) s = NPTS - WINW;

    if (tid < 8) qcnt[tid] = 0;

    float qx[8], qy[8], qz[8], q2[8];
    v2f smax2[8];
#pragma unroll
    for (int q = 0; q < 8; ++q) {
        float4 qp = psb[q0s + q];
        qx[q] = rfl(qp.x); qy[q] = rfl(qp.y); qz[q] = rfl(qp.z);
        q2[q] = rfl(-(qp.w + qp.w));      // |q|^2
        smax2[q] = splat2(-INFINITY);
    }

    // half-wave-chunk interleave: chunk = 64 points; chunk c -> wave c&3;
    // iter t covers local chunks 2t (lanes<32) and 2t+1 (lanes>=32).
    const int lbase = s + (((lane >> 5) * 4 + wv) << 6) + ((lane & 31) << 1);

    // ---- pass 1: per-lane max over this wave's share of the window ----
#pragma unroll
    for (int t = 0; t < WITR; ++t) {
        float4 p0 = psb[lbase + t * 512];
        float4 p1 = psb[lbase + t * 512 + 1];
        v2f px = { p0.x, p1.x }, py = { p0.y, p1.y };
        v2f pz = { p0.z, p1.z }, pw = { p0.w, p1.w };
#pragma unroll
        for (int q = 0; q < 8; ++q) {
            v2f sv = __builtin_elementwise_fma(splat2(qx[q]), px,
                     __builtin_elementwise_fma(splat2(qy[q]), py,
                     __builtin_elementwise_fma(splat2(qz[q]), pz, pw)));
            smax2[q] = __builtin_elementwise_max(smax2[q], sv);
        }
    }
#pragma unroll
    for (int q = 0; q < 8; ++q) smaxs[wv][q][lane] = fmaxf(smax2[q].x, smax2[q].y);
    __syncthreads();

    // ---- gate: combine 4 wave-shares elementwise; each wave sorts 2 q's ----
#pragma unroll
    for (int qq = 0; qq < 2; ++qq) {
        const int q = wv * 2 + qq;
        float v = fmaxf(fmaxf(smaxs[0][q][lane], smaxs[1][q][lane]),
                        fmaxf(smaxs[2][q][lane], smaxs[3][q][lane]));
#pragma unroll
        for (int k = 2; k <= 64; k <<= 1)
#pragma unroll
            for (int j = k >> 1; j >= 1; j >>= 1) {
                float o = __shfl_xor(v, j);
                bool up = ((lane & k) == 0);
                bool keepmin = (((lane & j) == 0) == up);
                v = keepmin ? fminf(v, o) : fmaxf(v, o);
            }
        float m = __shfl(v, 44);          // provable LB on window 20th-best
        if (lane == 0) gates[q] = m - 1e-4f - 1e-5f * fabsf(m);
    }
    __syncthreads();
    float sgate[8];
#pragma unroll
    for (int q = 0; q < 8; ++q) sgate[q] = gates[q];

    // ---- pass 2: gated append into the SHARED per-query queues ----
#pragma unroll
    for (int t = 0; t < WITR; ++t) {
        const int jb = lbase + t * 512;
        float4 p0 = psb[jb];
        float4 p1 = psb[jb + 1];
        v2f px = { p0.x, p1.x }, py = { p0.y, p1.y };
        v2f pz = { p0.z, p1.z }, pw = { p0.w, p1.w };
#pragma unroll
        for (int q = 0; q < 8; ++q) {
            v2f sv = __builtin_elementwise_fma(splat2(qx[q]), px,
                     __builtin_elementwise_fma(splat2(qy[q]), py,
                     __builtin_elementwise_fma(splat2(qz[q]), pz, pw)));
            if (fmaxf(sv.x, sv.y) >= sgate[q]) {     // common case: wave skips
#pragma unroll
                for (int h = 0; h < 2; ++h) {
                    float svh = h ? sv.y : sv.x;
                    if (svh >= sgate[q]) {
                        int slot = atomicAdd(&qcnt[q], 1);
                        if (slot < FQC)
                            queue[q][slot] = packkey(svh, six[jb + h], jb + h);
                    }
                }
            }
        }
    }
    __syncthreads();

    // ---- analytic window bounds from bin edges ----
    float xLe = (s == 0) ? -3.0e38f
                         : (BIN_LO + (float)(bob[s] + 1) * BIN_W);        // e_hi(bin at s)
    float xRe = (s == NPTS - WINW) ? 3.0e38f
                         : (BIN_LO + (float)bob[s + WINW] * BIN_W);       // e_lo(bin at s+WINW)

    // ---- final: sort each query's shared queue, emit, verify ----
#pragma unroll
    for (int qq = 0; qq < 2; ++qq) {
        const int q = wv * 2 + qq;
        const int cr = qcnt[q];
        const bool ovf = (cr > FQC);
        const int c = cr < FQC ? cr : FQC;
        unsigned long long key = (lane < c) ? queue[q][lane] : 0ull;
#pragma unroll
        for (int k = 2; k <= 64; k <<= 1)
#pragma unroll
            for (int j = k >> 1; j >= 1; j >>= 1) {
                unsigned long long o = __shfl_xor(key, j);
                bool up = ((lane & k) == 0);
                bool keepmax = (((lane & j) == 0) == up);
                bool omax = o > key;
                key = (keepmax == omax) ? o : key;
            }
        if (lane < KNN)
            idx_out[(b * KNN + lane) * NPTS + (q0s + q)] =   // [b][k][n] sorted col
                (int)(unsigned)(key & 0x1FFFu);              // SORTED slot

        // verify: queue complete AND true 20-NN cannot live outside window
        unsigned long long k19 = __shfl(key, 19);
        float s20 = fdec((unsigned)(k19 >> 32));
        float d20 = fmaxf(q2[q] - 2.0f * s20, 0.0f);    // d20^2
        float mg  = 1e-3f + 1e-3f * d20;
        float dL  = qx[q] - xLe;
        float dR  = xRe - qx[q];
        bool ok = !ovf && (c >= KNN) && dL > 0.0f && dR > 0.0f
                  && (d20 + mg < dL * dL) && (d20 + mg < dR * dR);
        if (!ok && lane == 0) {
            unsigned fs = atomicAdd(&fcnt[b], 1u);
            if (fs < 8192u) flist[b * 8192 + fs] = q0s + q;  // sorted slot
        }
    }
}

// ---------------------------------------------------------------------------
// K1b: exact full-scan fallback, 2 queries per block-task, SHARED cap-64
// queue per query (cluster-proof — R2 lesson). grid: 4096 x 256.
// ---------------------------------------------------------------------------
__global__ __launch_bounds__(256, 8) void knn_fb_kernel(const float4* __restrict__ psort,
                                                        const int* __restrict__ sidx,
                                                        int* __restrict__ idx_out,
                                                        const unsigned* __restrict__ fcnt,
                                                        const int* __restrict__ flist)
{
    __shared__ unsigned long long queue[2][FQC];   // per-QUERY shared queues, 1 KB
    __shared__ float smaxs[4][2][64];
    __shared__ float gates[2];
    __shared__ int qcnt[2];

    const int tid  = threadIdx.x;
    const int lane = tid & 63;
    const int wv   = tid >> 6;
    const int bb   = blockIdx.x & 3;
    unsigned cnt = fcnt[bb];
    if (cnt > 8192u) cnt = 8192u;
    if (cnt == 0u) return;
    const float4* pb = psort + bb * NPTS;
    const int* six = sidx + bb * NPTS;
    const int* fl = flist + bb * 8192;
    const int cbase = wv * (NPTS / 4);
    const int tstep = gridDim.x >> 2;

    for (int task = blockIdx.x >> 2; task * 2 < (int)cnt; task += tstep) {
        int qs[2];
        float qx[2], qy[2], qz[2];
        v2f smax2[2];
        if (tid < 2) qcnt[tid] = 0;
#pragma unroll
        for (int q = 0; q < 2; ++q) {
            int e = task * 2 + q;
            if (e >= (int)cnt) e = (int)cnt - 1;      // pad with dup (benign)
            qs[q] = __builtin_amdgcn_readfirstlane(fl[e]);
            float4 qp = pb[qs[q]];
            qx[q] = rfl(qp.x); qy[q] = rfl(qp.y); qz[q] = rfl(qp.z);
            smax2[q] = splat2(-INFINITY);
        }

#pragma unroll 4
        for (int t = 0; t < NPTS / 4 / 128; ++t) {
            float4 p0 = pb[cbase + t * 128 + 2 * lane];
            float4 p1 = pb[cbase + t * 128 + 2 * lane + 1];
            v2f px = { p0.x, p1.x }, py = { p0.y, p1.y };
            v2f pz = { p0.z, p1.z }, pw = { p0.w, p1.w };
#pragma unroll
            for (int q = 0; q < 2; ++q) {
                v2f sv = __builtin_elementwise_fma(splat2(qx[q]), px,
                         __builtin_elementwise_fma(splat2(qy[q]), py,
                         __builtin_elementwise_fma(splat2(qz[q]), pz, pw)));
                smax2[q] = __builtin_elementwise_max(smax2[q], sv);
            }
        }
#pragma unroll
        for (int q = 0; q < 2; ++q) smaxs[wv][q][lane] = fmaxf(smax2[q].x, smax2[q].y);
        __syncthreads();

        if (wv < 2) {
            const int q = wv;
            float v = fmaxf(fmaxf(smaxs[0][q][lane], smaxs[1][q][lane]),
                            fmaxf(smaxs[2][q][lane], smaxs[3][q][lane]));
#pragma unroll
            for (int k = 2; k <= 64; k <<= 1)
#pragma unroll
                for (int j = k >> 1; j >= 1; j >>= 1) {
                    float o = __shfl_xor(v, j);
                    bool up = ((lane & k) == 0);
                    bool keepmin = (((lane & j) == 0) == up);
                    v = keepmin ? fminf(v, o) : fmaxf(v, o);
                }
            float m = __shfl(v, 44);
            if (lane == 0) gates[q] = m - 1e-4f - 1e-5f * fabsf(m);
        }
        __syncthreads();
        float sg0 = gates[0], sg1 = gates[1];

        for (int t = 0; t < NPTS / 4 / 128; ++t) {
            const int jb = cbase + t * 128 + 2 * lane;
            float4 p0 = pb[jb];
            float4 p1 = pb[jb + 1];
            v2f px = { p0.x, p1.x }, py = { p0.y, p1.y };
            v2f pz = { p0.z, p1.z }, pw = { p0.w, p1.w };
#pragma unroll
            for (int q = 0; q < 2; ++q) {
                float sg = q ? sg1 : sg0;
                v2f sv = __builtin_elementwise_fma(splat2(qx[q]), px,
                         __builtin_elementwise_fma(splat2(qy[q]), py,
                         __builtin_elementwise_fma(splat2(qz[q]), pz, pw)));
                if (fmaxf(sv.x, sv.y) >= sg) {
#pragma unroll
                    for (int h = 0; h < 2; ++h) {
                        float svh = h ? sv.y : sv.x;
                        if (svh >= sg) {
                            int slot = atomicAdd(&qcnt[q], 1);
                            if (slot < FQC)
                                queue[q][slot] = packkey(svh, six[jb + h], jb + h);
                        }
                    }
                }
            }
        }
        __syncthreads();

        if (wv < 2) {
            const int q = wv;
            int c = qcnt[q]; c = c < FQC ? c : FQC;
            unsigned long long key = (lane < c) ? queue[q][lane] : 0ull;
#pragma unroll
            for (int k = 2; k <= 64; k <<= 1)
#pragma unroll
                for (int j = k >> 1; j >= 1; j >>= 1) {
                    unsigned long long o = __shfl_xor(key, j);
                    bool up = ((lane & k) == 0);
                    bool keepmax = (((lane & j) == 0) == up);
                    bool omax = o > key;
                    key = (keepmax == omax) ? o : key;
                }
            if (lane < KNN)
                idx_out[(bb * KNN + lane) * NPTS + qs[q]] =
                    (int)(unsigned)(key & 0x1FFFu);
        }
        __syncthreads();   // protect LDS reuse by next task
    }
}

// ---------------------------------------------------------------------------
// K2: x0 moments (6 sums + 21 upper-tri products) — SORTED domain. R7: plain
// again (R6's per-block __threadfence for the fused finalize1 was the
// regression: agent-scope fence = L2 writeback per block).
// ---------------------------------------------------------------------------
__global__ __launch_bounds__(256) void moments_x_kernel(const float4* __restrict__ psort,
                                                        const int* __restrict__ idx,
                                                        float* __restrict__ sums1p)
{
    const int b  = blockIdx.x / 80;
    const int r0 = (blockIdx.x - b * 80) * 2048;
    const float4* pb = psort + b * NPTS;
    const int* ib = idx + b * NKTOT;

    float v[27];
#pragma unroll
    for (int i = 0; i < 27; ++i) v[i] = 0.f;

    for (int e = 0; e < 8; ++e) {
        const int id = r0 + e * 256 + threadIdx.x;   // [k][n] linear, coalesced
        const int n = id & (NPTS - 1);
        const int j = ib[id];
        float4 c4 = pb[n];
        float4 e4 = pb[j];
        float x[6] = { c4.x, c4.y, c4.z, e4.x - c4.x, e4.y - c4.y, e4.z - c4.z };
        int p = 6;
#pragma unroll
        for (int d = 0; d < 6; ++d) {
            v[d] += x[d];
#pragma unroll
            for (int ee = d; ee < 6; ++ee) v[p++] += x[d] * x[ee];
        }
    }
#pragma unroll
    for (int i = 0; i < 27; ++i)
        for (int o = 32; o > 0; o >>= 1) v[i] += __shfl_xor(v[i], o);

    __shared__ float red[4][27];
    const int lane = threadIdx.x & 63, w = threadIdx.x >> 6;
    if (lane == 0)
#pragma unroll
        for (int i = 0; i < 27; ++i) red[w][i] = v[i];
    __syncthreads();
    if (threadIdx.x < 27) {
        float acc = red[0][threadIdx.x] + red[1][threadIdx.x] + red[2][threadIdx.x] + red[3][threadIdx.x];
        int slot = blockIdx.x & 63;
        atomicAdd(&sums1p[(slot * BATCH + b) * 27 + threadIdx.x], acc);
    }
}

// ---------------------------------------------------------------------------
// K3: finalize GN1 stats -> folded per-channel weights w1f[b][c][8].
// ---------------------------------------------------------------------------
__global__ void finalize1_kernel(const float* __restrict__ sums1p,
                                 const float* __restrict__ w1, const float* __restrict__ b1,
                                 const float* __restrict__ g1, const float* __restrict__ beta1,
                                 float* __restrict__ w1f)
{
    __shared__ float S[BATCH][27];
    const int t = threadIdx.x;
    if (t < 108) {
        int b = t / 27, i = t % 27;
        float acc = 0.f;
        for (int s = 0; s < 64; ++s) acc += sums1p[(s * BATCH + b) * 27 + i];
        S[b][i] = acc;
    }
    __syncthreads();
    const int b = t >> 5, c = t & 31;
    const float invS = 1.0f / (float)NKTOT;
    float Ex[6], M[6][6];
#pragma unroll
    for (int d = 0; d < 6; ++d) Ex[d] = S[b][d] * invS;
    int p = 6;
#pragma unroll
    for (int d = 0; d < 6; ++d)
#pragma unroll
        for (int e = d; e < 6; ++e) { float v = S[b][p++] * invS; M[d][e] = v; M[e][d] = v; }
    const int g = c >> 2;
    float msum = 0.f, qsum = 0.f;
    for (int cc = g * 4; cc < g * 4 + 4; ++cc) {
        float w[6];
#pragma unroll
        for (int d = 0; d < 6; ++d) w[d] = w1[cc * 6 + d];
        float dotEx = 0.f;
#pragma unroll
        for (int d = 0; d < 6; ++d) dotEx += w[d] * Ex[d];
        float Ey = dotEx + b1[cc];
        float Ey2 = 0.f;
#pragma unroll
        for (int d = 0; d < 6; ++d)
#pragma unroll
            for (int e = 0; e < 6; ++e) Ey2 += w[d] * w[e] * M[d][e];
        Ey2 += 2.0f * b1[cc] * dotEx + b1[cc] * b1[cc];
        msum += Ey; qsum += Ey2;
    }
    float m = msum * 0.25f;
    float var = qsum * 0.25f - m * m;
    float inv = rsqrtf(var + EPS);
    float s = g1[c] * inv;
    float tt = s * (b1[c] - m) + beta1[c];
    float* o = w1f + (b * 32 + c) * 8;
#pragma unroll
    for (int d = 0; d < 6; ++d) o[d] = s * w1[c * 6 + d];
    o[6] = tt; o[7] = 0.f;
}

// ---------------------------------------------------------------------------
// K4: fused main pass (SORTED domain). R7: plain again (no epilogue/fence).
// ---------------------------------------------------------------------------
__global__ __launch_bounds__(256, 3) void fused_main_kernel(
    const float4* __restrict__ psort, const int* __restrict__ idxb,
    const float* __restrict__ w1f, const float* __restrict__ w2, const float* __restrict__ b2,
    float* __restrict__ sums2p, unsigned int* __restrict__ maxenc, unsigned int* __restrict__ minenc)
{
    __shared__ __align__(16) float w2t[32 * 64];    // W2^T: [k][c]   8 KB
    __shared__ __align__(16) float z1s[32 * 256];   // z1:   [k][n]  32 KB
    __shared__ __align__(16) float4 w1s4[64];       // folded W1 [32][8]
    __shared__ float b2s[64];
    __shared__ float redmx[256], redmn[256], sqred[64];

    const int t   = threadIdx.x;
    const int blk = blockIdx.x;
    const int nc  = blk & 15;
    const int k   = (blk >> 4) % 20;
    const int b   = blk / 320;          // 320 blocks per batch (16 nc * 20 k)

    for (int i = t; i < 512; i += 256) {
        float4 v = ((const float4*)w2)[i];
        int c = i >> 3, kq = (i & 7) * 4;
        w2t[(kq + 0) * 64 + c] = v.x; w2t[(kq + 1) * 64 + c] = v.y;
        w2t[(kq + 2) * 64 + c] = v.z; w2t[(kq + 3) * 64 + c] = v.w;
    }
    if (t < 64) { w1s4[t] = ((const float4*)w1f)[b * 64 + t]; b2s[t] = b2[t]; }

    const int wvi = t >> 6;
    const int cg8 = t & 7;            // channel octet == GN group (GEMM)
    const int n0  = (t >> 3) * 8;     // n-group base 0..248 (GEMM)
    const int c0  = cg8 * 8;
    const float4* pb = psort + b * NPTS;
    const int nbase = nc * 512;
    const int* idxrow = idxb + (b * KNN + k) * NPTS;   // [b][k][n]: coalesced

    float mx[8], mn[8];
#pragma unroll
    for (int ci = 0; ci < 8; ++ci) { mx[ci] = -INFINITY; mn[ci] = INFINITY; }
    float gs = 0.f, gq = 0.f;

    for (int ph = 0; ph < 2; ++ph) {
        // ---- fill z1[32][256]: thread owns n = nbase+ph*256+t, all 32 ch ----
        const int n = nbase + ph * 256 + t;
        const int j = idxrow[n];
        float4 c4 = pb[n];
        float4 e4 = pb[j];
        float x0[6] = { c4.x, c4.y, c4.z, e4.x - c4.x, e4.y - c4.y, e4.z - c4.z };

        __syncthreads();   // staging done (ph=0) / previous GEMM reads done
#pragma unroll
        for (int c = 0; c < 32; ++c) {
            float4 wA = w1s4[c * 2 + 0];
            float4 wB = w1s4[c * 2 + 1];
            float z = wB.z;
            z = fmaf(wA.x, x0[0], z); z = fmaf(wA.y, x0[1], z); z = fmaf(wA.z, x0[2], z);
            z = fmaf(wA.w, x0[3], z); z = fmaf(wB.x, x0[4], z); z = fmaf(wB.y, x0[5], z);
            z1s[c * 256 + t] = eluf(z);
        }
        __syncthreads();

        // ---- GEMM: 8c x 8n per thread, 4 b128 per 64 FMA ----
        float acc[8][8];
#pragma unroll
        for (int ci = 0; ci < 8; ++ci) {
            float bb = b2s[c0 + ci];
#pragma unroll
            for (int pj = 0; pj < 8; ++pj) acc[ci][pj] = bb;
        }
#pragma unroll
        for (int kk = 0; kk < 32; ++kk) {
            float4 a0 = *(const float4*)&w2t[kk * 64 + c0];
            float4 a1 = *(const float4*)&w2t[kk * 64 + c0 + 4];
            float4 z0 = *(const float4*)&z1s[kk * 256 + n0];
            float4 z1v = *(const float4*)&z1s[kk * 256 + n0 + 4];
            float avv[8] = { a0.x, a0.y, a0.z, a0.w, a1.x, a1.y, a1.z, a1.w };
            float zvv[8] = { z0.x, z0.y, z0.z, z0.w, z1v.x, z1v.y, z1v.z, z1v.w };
#pragma unroll
            for (int ci = 0; ci < 8; ++ci)
#pragma unroll
                for (int pj = 0; pj < 8; ++pj) acc[ci][pj] = fmaf(avv[ci], zvv[pj], acc[ci][pj]);
        }
#pragma unroll
        for (int ci = 0; ci < 8; ++ci)
#pragma unroll
            for (int pj = 0; pj < 8; ++pj) {
                float v = acc[ci][pj];
                gs += v; gq = fmaf(v, v, gq);
                mx[ci] = fmaxf(mx[ci], v); mn[ci] = fminf(mn[ci], v);
            }
    }

    // reduce over the 8 n-groups within this wave (lane bits 3,4,5)
#pragma unroll
    for (int m = 8; m <= 32; m <<= 1) {
#pragma unroll
        for (int ci = 0; ci < 8; ++ci) {
            mx[ci] = fmaxf(mx[ci], __shfl_xor(mx[ci], m));
            mn[ci] = fminf(mn[ci], __shfl_xor(mn[ci], m));
        }
        gs += __shfl_xor(gs, m);
        gq += __shfl_xor(gq, m);
    }
    if ((t & 63) < 8) {
        const int l = t & 7;
#pragma unroll
        for (int ci = 0; ci < 8; ++ci) {
            redmx[wvi * 64 + l * 8 + ci] = mx[ci];
            redmn[wvi * 64 + l * 8 + ci] = mn[ci];
        }
        sqred[(wvi * 8 + l) * 2 + 0] = gs;
        sqred[(wvi * 8 + l) * 2 + 1] = gq;
    }
    __syncthreads();
    if (t < 64) {
        float m = fmaxf(fmaxf(redmx[t], redmx[64 + t]), fmaxf(redmx[128 + t], redmx[192 + t]));
        atomicMax(&maxenc[(b * 64 + t) * KNN + k], fenc(m));
    } else if (t < 128) {
        int c = t - 64;
        float m = fminf(fminf(redmn[c], redmn[64 + c]), fminf(redmn[128 + c], redmn[192 + c]));
        atomicMin(&minenc[(b * 64 + c) * KNN + k], fenc(m));
    } else if (t < 144) {
        int i2 = t - 128, g = i2 >> 1, w = i2 & 1;
        float v = 0.f;
#pragma unroll
        for (int wv2 = 0; wv2 < 4; ++wv2)
            v += sqred[(wv2 * 8 + g) * 2 + w];
        int slot = blk & 63;
        atomicAdd(&sums2p[((slot * BATCH + b) * 8 + g) * 2 + w], v);
    }
}

// ---------------------------------------------------------------------------
// K5: build m1[b,c,k] = ELU(GN2-affine applied to max-or-min over n of y2)
// ---------------------------------------------------------------------------
__global__ void build_m1_kernel(const float* __restrict__ sums2p,
                                const unsigned int* __restrict__ maxenc,
                                const unsigned int* __restrict__ minenc,
                                const float* __restrict__ gamma, const float* __restrict__ beta,
                                float* __restrict__ m1)
{
    const int t = blockIdx.x * 256 + threadIdx.x;   // (b*64+c)*20+k
    const int b = t / 1280;
    const int r = t - b * 1280;
    const int c = r / 20;
    const int g = c >> 3;
    float s = 0.f, q = 0.f;
    for (int sl = 0; sl < 64; ++sl) {
        s += sums2p[((sl * BATCH + b) * 8 + g) * 2 + 0];
        q += sums2p[((sl * BATCH + b) * 8 + g) * 2 + 1];
    }
    const float cnt = 8.0f * (float)NKTOT;
    float m = s / cnt;
    float var = q / cnt - m * m;
    float inv = rsqrtf(var + EPS);
    float sc = gamma[c] * inv;
    float tt = beta[c] - sc * m;
    float y = (sc >= 0.f) ? fdec(maxenc[t]) : fdec(minenc[t]);
    m1[t] = elu(sc * y + tt);
}

// ---------------------------------------------------------------------------
// K6/K8: pointwise conv (CIN -> COUT over K=20) + raw output + GN stat partials
// ---------------------------------------------------------------------------
template <int CIN, int SLOTS>
__global__ void p2_gemm_kernel(const float* __restrict__ zin, const float* __restrict__ w,
                               const float* __restrict__ bias, float* __restrict__ yout,
                               float* __restrict__ sumsp, int chans_per_group)
{
    const int t = blockIdx.x * 256 + threadIdx.x;
    const int per_b = (gridDim.x * 256) / BATCH;
    const int b = t / per_b;
    const int r = t - b * per_b;
    const int o = r / 20;
    const int k = r - o * 20;
    const float* zb = zin + b * CIN * 20;
    const float* wrow = w + o * CIN;
    float acc = bias[o];
    for (int c = 0; c < CIN; c += 4) {
        float4 wv = *(const float4*)&wrow[c];
        acc += wv.x * zb[(c + 0) * 20 + k] + wv.y * zb[(c + 1) * 20 + k]
             + wv.z * zb[(c + 2) * 20 + k] + wv.w * zb[(c + 3) * 20 + k];
    }
    yout[t] = acc;

    __shared__ float ls[16];
    if (threadIdx.x < 16) ls[threadIdx.x] = 0.f;
    __syncthreads();
    const int g = o / chans_per_group;
    atomicAdd(&ls[g * 2 + 0], acc);
    atomicAdd(&ls[g * 2 + 1], acc * acc);
    __syncthreads();
    if (threadIdx.x < 16) {
        int slot = blockIdx.x & (SLOTS - 1);
        atomicAdd(&sumsp[(slot * BATCH + b) * 16 + threadIdx.x], ls[threadIdx.x]);
    }
}

// K7/K9: apply GN affine + ELU using partial sums
template <int SLOTS>
__global__ void p2_finalize_kernel(const float* __restrict__ y, const float* __restrict__ sumsp,
                                   const float* __restrict__ gamma, const float* __restrict__ beta,
                                   float* __restrict__ z, int chans_per_group, float cnt)
{
    const int t = blockIdx.x * 256 + threadIdx.x;
    const int per_b = (gridDim.x * 256) / BATCH;
    const int b = t / per_b;
    const int r = t - b * per_b;
    const int o = r / 20;
    const int g = o / chans_per_group;
    float s = 0.f, q = 0.f;
    for (int sl = 0; sl < SLOTS; ++sl) {
        s += sumsp[(sl * BATCH + b) * 16 + g * 2 + 0];
        q += sumsp[(sl * BATCH + b) * 16 + g * 2 + 1];
    }
    float m = s / cnt;
    float var = q / cnt - m * m;
    float inv = rsqrtf(var + EPS);
    float v = gamma[o] * inv * (y[t] - m) + beta[o];
    z[t] = elu(v);
}

// ---------------------------------------------------------------------------
extern "C" void kernel_launch(void* const* d_in, const int* in_sizes, int n_in,
                              void* d_out, int out_size, void* d_ws, size_t ws_size,
                              hipStream_t stream)
{
    const float* points  = (const float*)d_in[0];
    const float* p1_w0   = (const float*)d_in[1];
    const float* p1_b0   = (const float*)d_in[2];
    const float* p1_g0   = (const float*)d_in[3];
    const float* p1_bt0  = (const float*)d_in[4];
    const float* p1_w1   = (const float*)d_in[5];
    const float* p1_b1   = (const float*)d_in[6];
    const float* p1_g1   = (const float*)d_in[7];
    const float* p1_bt1  = (const float*)d_in[8];
    const float* p2_w0   = (const float*)d_in[9];
    const float* p2_b0   = (const float*)d_in[10];
    const float* p2_g0   = (const float*)d_in[11];
    const float* p2_bt0  = (const float*)d_in[12];
    const float* p2_w1   = (const float*)d_in[13];
    const float* p2_b1   = (const float*)d_in[14];
    const float* p2_g1   = (const float*)d_in[15];
    const float* p2_bt1  = (const float*)d_in[16];
    float* out = (float*)d_out;

    float* ws = (float*)d_ws;
    int*      idx     = (int*)ws;                    // 655360  ([b][k][n], sorted cols)
    float*    sums1p  = ws + 655360;                 // 6912   (zeroed by prep)
    float*    sums2p  = sums1p + 6912;               // 4096   (zeroed by prep)
    float*    sumsAp  = sums2p + 4096;               // 1024   (zeroed by prep)
    float*    sumsBp  = sumsAp + 1024;               // 1024   (zeroed by prep)
    unsigned* maxenc  = (unsigned*)(sumsBp + 1024);  // 5120   (zeroed by prep)
    unsigned* minenc  = maxenc + 5120;               // 5120   (0xFF by prep)
    float*    w1f     = (float*)(minenc + 5120);     // 1024
    float*    m1      = w1f + 1024;                  // 5120
    float*    yp2a    = m1 + 5120;                   // 40960
    float*    zp2a    = yp2a + 40960;                // 40960
    float*    yp2b    = zp2a + 40960;                // 81920
    // pts4 (original order) aliases yp2a onward; live only until scatter.
    float4*   pts4    = (float4*)yp2a;
    // hist partials alias the idx region (consumed by scatter BEFORE knn writes idx)
    int*      Pcur_part = idx;                       // 131072 ints, transient
    // sorted-domain arrays (fresh space after yp2b; psort lives through fused_main)
    float*    psortf  = yp2b + 81920;                // 131072 (float4[4][8192])
    float4*   psort4  = (float4*)psortf;
    int*      sidx    = (int*)(psortf + 131072);     // 32768
    int*      binof   = sidx + 32768;                // 32768 (+64 pad)
    unsigned* fcnt8   = (unsigned*)(binof + 32768 + 64); // 8 (+56 pad)
    int*      flist   = (int*)(fcnt8 + 64);          // 32768 (4 x 8192 per-batch lists)

    // zero region = sums1p..maxenc contiguous: 6912+4096+1024+1024+5120 = 18176
    prep_kernel<<<128, 256, 0, stream>>>(points, pts4, sums1p, minenc, fcnt8, Pcur_part);
    scatter_kernel<<<128, 256, 0, stream>>>(pts4, Pcur_part, psort4, sidx, binof);
    knn_win_kernel<<<4096, 256, 0, stream>>>(psort4, sidx, binof, idx, fcnt8, flist);
    knn_fb_kernel<<<4096, 256, 0, stream>>>(psort4, sidx, idx, fcnt8, flist);
    moments_x_kernel<<<320, 256, 0, stream>>>(psort4, idx, sums1p);
    finalize1_kernel<<<1, 128, 0, stream>>>(sums1p, p1_w0, p1_b0, p1_g0, p1_bt0, w1f);
    // grid MUST be 1280 = 4 b * 20 k * 16 nc  (b = blk/320; larger grids give
    // b >= BATCH -> OOB idx reads -> memory fault, see R4 crash)
    fused_main_kernel<<<1280, 256, 0, stream>>>(psort4, idx, w1f, p1_w1, p1_b1,
                                                sums2p, maxenc, minenc);
    build_m1_kernel<<<20, 256, 0, stream>>>(sums2p, maxenc, minenc, p1_g1, p1_bt1, m1);
    p2_gemm_kernel<64, 16><<<160, 256, 0, stream>>>(m1, p2_w0, p2_b0, yp2a, sumsAp, 64);
    p2_finalize_kernel<16><<<160, 256, 0, stream>>>(yp2a, sumsAp, p2_g0, p2_bt0, zp2a, 64, 1280.0f);
    p2_gemm_kernel<512, 16><<<320, 256, 0, stream>>>(zp2a, p2_w1, p2_b1, yp2b, sumsBp, 128);
    p2_finalize_kernel<16><<<320, 256, 0, stream>>>(yp2b, sumsBp, p2_g1, p2_bt1, out, 128, 2560.0f);
}

// Round 8
// 266.386 us; speedup vs baseline: 1.5581x; 1.2506x over previous
//
#include <hip/hip_runtime.h>
#include <math.h>

#define NPTS   8192
#define BATCH  4
#define KNN    20
#define NKTOT  (NPTS*KNN)        // 163840 spatial positions per batch
#define EPS    1e-5f
#define FQC    64                // per-query SHARED queue cap (cluster-proof)

// windowed-KNN parameters — R8: REVERTED to the R4 measured-good config
// (knn_win 63.4us). R5's WINW=2048 single-window was a 2x regression
// (112-119us, VALU 35%, fallback rate ~7x) — see R7 post-mortem.
#define WINW   3072              // sorted-x window width (pass 2, completeness)
#define WITR   (WINW/4/128)      // 6 iterations of 128 candidates per wave
#define GWIN   2048              // pass-1 gate window (subset => provable gate)
#define GITR   (GWIN/4/128)      // 4 iterations
#define NBIN   1024
#define BIN_LO (-4.5f)
#define BIN_W  (9.0f/1024.0f)

typedef float v2f __attribute__((ext_vector_type(2)));

__device__ __forceinline__ float elu(float x) { return x > 0.0f ? x : expm1f(x); }
__device__ __forceinline__ float eluf(float x) { return x > 0.0f ? x : __expf(x) - 1.0f; }
__device__ __forceinline__ v2f splat2(float x) { v2f v; v.x = x; v.y = x; return v; }
__device__ __forceinline__ float rfl(float x) {
    return __uint_as_float(__builtin_amdgcn_readfirstlane(__float_as_uint(x)));
}

// monotone float <-> unsigned encoding for atomic max/min on floats
__device__ __forceinline__ unsigned fenc(float f) {
    unsigned b = __float_as_uint(f);
    return b ^ ((unsigned)(((int)b) >> 31) | 0x80000000u);
}
__device__ __forceinline__ float fdec(unsigned u) {
    unsigned b = (u & 0x80000000u) ? (u ^ 0x80000000u) : ~u;
    return __uint_as_float(b);
}

// x-bin assignment — MUST be the identical expression everywhere it is used
__device__ __forceinline__ int xbin(float x) {
    int bin = (int)floorf((x + 4.5f) * (1024.0f / 9.0f));
    return bin < 0 ? 0 : (bin > NBIN - 1 ? NBIN - 1 : bin);
}

// key packing: [score:32 | (8191-orig):13 | slot:13].  Descending sort order
// == (score desc, original-index asc) — exact lax.top_k tie-break — while the
// low 13 bits carry the SORTED slot we emit (downstream works in sorted domain).
__device__ __forceinline__ unsigned long long packkey(float s, int orig, int slot) {
    return ((unsigned long long)fenc(s) << 32)
         | (unsigned)(((NPTS - 1 - orig) << 13) | slot);
}

// ---------------------------------------------------------------------------
// K0: pack points into (x,y,z,-0.5*|p|^2), init accumulator workspace, AND
// build per-block x-histogram partials (each block covers 256 points of one
// batch; 32 blocks per batch).
// ---------------------------------------------------------------------------
__global__ __launch_bounds__(256) void prep_kernel(const float* __restrict__ points,
                                                   float4* __restrict__ pts4,
                                                   float* __restrict__ zeroreg,   // 18176 words
                                                   unsigned* __restrict__ minenc, // 5120 words
                                                   unsigned* __restrict__ fcnt,   // 8 words
                                                   int* __restrict__ Pcur_part)   // 128*1024
{
    __shared__ int lh[NBIN];
    const int t = blockIdx.x * 256 + threadIdx.x;     // 32768
    const int b = t >> 13, n = t & (NPTS - 1);
    for (int i = threadIdx.x; i < NBIN; i += 256) lh[i] = 0;
    const float* px = points + b * 3 * NPTS;
    float x = px[n], y = px[NPTS + n], z = px[2 * NPTS + n];
    pts4[t] = make_float4(x, y, z, -0.5f * (x * x + y * y + z * z));
    if (t < 18176) zeroreg[t] = 0.f;
    if (t < 5120)  minenc[t] = 0xFFFFFFFFu;
    if (t < 8)     fcnt[t] = 0u;   // [0..3]=fb counters, rest spare
    __syncthreads();
    atomicAdd(&lh[xbin(x)], 1);
    __syncthreads();
    for (int i = threadIdx.x; i < NBIN; i += 256)
        Pcur_part[blockIdx.x * NBIN + i] = lh[i];
}

// ---------------------------------------------------------------------------
// K0c: scatter into bin-ordered layout. Each block redundantly rebuilds the
// global prefix from the 32 per-block partials (no serialized scan kernel)
// and derives exact slots as
//   global_excl_prefix[bin] + count-in-earlier-blocks[bin] + local rank
// — no global atomics. Within-bin order nondeterministic only within a block
// (irrelevant: analytic bin-edge bounds; network is a set-op in n).
// ---------------------------------------------------------------------------
__global__ __launch_bounds__(256) void scatter_kernel(const float4* __restrict__ pts4,
                                                      const int* __restrict__ Pcur_part,
                                                      float4* __restrict__ psort,
                                                      int* __restrict__ sidx,
                                                      int* __restrict__ binof)
{
    __shared__ int boff[NBIN];     // per-bin slot base for THIS block
    __shared__ int brank[NBIN];    // within-block rank counters
    __shared__ int wsum[256];
    const int jb = blockIdx.x & 31;       // block index within batch
    const int b  = blockIdx.x >> 5;
    const int tt = threadIdx.x;
    const int t0 = tt * 4;                // this thread owns bins [t0, t0+4)

    int tot0 = 0, tot1 = 0, tot2 = 0, tot3 = 0;
    int pre0 = 0, pre1 = 0, pre2 = 0, pre3 = 0;
    for (int p = 0; p < 32; ++p) {
        const int4 c = *(const int4*)&Pcur_part[(b * 32 + p) * NBIN + t0];
        tot0 += c.x; tot1 += c.y; tot2 += c.z; tot3 += c.w;
        if (p < jb) { pre0 += c.x; pre1 += c.y; pre2 += c.z; pre3 += c.w; }
    }
    const int tsum = tot0 + tot1 + tot2 + tot3;
    wsum[tt] = tsum;
    __syncthreads();
    for (int off = 1; off < 256; off <<= 1) {          // Hillis-Steele incl scan
        int a = (tt >= off) ? wsum[tt - off] : 0;
        __syncthreads();
        wsum[tt] += a;
        __syncthreads();
    }
    int run = wsum[tt] - tsum;            // exclusive batch-prefix at bin t0
    boff[t0 + 0] = run + pre0; run += tot0;
    boff[t0 + 1] = run + pre1; run += tot1;
    boff[t0 + 2] = run + pre2; run += tot2;
    boff[t0 + 3] = run + pre3;
    for (int i = tt; i < NBIN; i += 256) brank[i] = 0;
    __syncthreads();

    const int n = jb * 256 + tt;
    float4 p = pts4[b * NPTS + n];
    int bin = xbin(p.x);
    int slot = boff[bin] + atomicAdd(&brank[bin], 1);
    psort[b * NPTS + slot] = p;
    sidx [b * NPTS + slot] = n;
    binof[b * NPTS + slot] = bin;
}

// ---------------------------------------------------------------------------
// K1: windowed exact KNN in the SORTED domain — R4 measured-good version
// (63.4us). Octet = 8 consecutive sorted positions. Pass 1 scans a GWIN=2048
// central subset for the gate: rank-44 of the 64 combined lane-maxima is a
// provable LB on the subset's 20th-best score, hence <= the window's
// 20th-best => every true window-top-20 passes the gate in pass 2 (which
// scans the full WINW=3072 window). ONE shared cap-64 queue per query (fed
// by all 4 waves via LDS atomics) — immune to sorted-x clustering; overflow
// (total>64) / short queue (<20) / window-incompleteness (d20^2 vs analytic
// bin-edge bounds) -> fallback worklist. Candidate interleave by half-wave
// chunk (64 points): each half-wave reads a contiguous 1KB segment.
// Output idx values are SORTED SLOTS at sorted column q0s+q. grid: 4096x256.
// ---------------------------------------------------------------------------
__global__ __launch_bounds__(256, 8) void knn_win_kernel(
    const float4* __restrict__ psort, const int* __restrict__ sidx,
    const int* __restrict__ binof, int* __restrict__ idx_out,
    unsigned* __restrict__ fcnt, int* __restrict__ flist)
{
    __shared__ unsigned long long queue[8][FQC];   // per-QUERY shared, 4 KB
    __shared__ float smaxs[4][8][64];              // 8 KB lane-maxima shares
    __shared__ float gates[8];
    __shared__ int qcnt[8];

    const int tid  = threadIdx.x;
    const int lane = tid & 63;
    const int wv   = tid >> 6;
    const int b    = blockIdx.x >> 10;    // 1024 blocks per batch
    const int oct  = blockIdx.x & 1023;
    const int q0s  = oct * 8;             // sorted-position base of this octet
    const float4* psb = psort + b * NPTS;
    const int*    six = sidx  + b * NPTS;
    const int*    bob = binof + b * NPTS;

    int s = q0s + 4 - WINW / 2;           // pass-2 window start
    if (s < 0) s = 0;
    if (s > NPTS - WINW) s = NPTS - WINW;
    int gs = q0s + 4 - GWIN / 2;          // pass-1 gate-subset start
    if (gs < 0) gs = 0;
    if (gs > NPTS - GWIN) gs = NPTS - GWIN;

    if (tid < 8) qcnt[tid] = 0;

    float qx[8], qy[8], qz[8], q2[8];
    v2f smax2[8];
#pragma unroll
    for (int q = 0; q < 8; ++q) {
        float4 qp = psb[q0s + q];
        qx[q] = rfl(qp.x); qy[q] = rfl(qp.y); qz[q] = rfl(qp.z);
        q2[q] = rfl(-(qp.w + qp.w));      // |q|^2
        smax2[q] = splat2(-INFINITY);
    }

    // half-wave-chunk interleave: chunk = 64 points; chunk c -> wave c&3;
    // iter t covers local chunks 2t (lanes<32) and 2t+1 (lanes>=32).
    const int gbase = gs + (((lane >> 5) * 4 + wv) << 6) + ((lane & 31) << 1);
    const int lbase = s  + (((lane >> 5) * 4 + wv) << 6) + ((lane & 31) << 1);

    // ---- pass 1: per-lane max over this wave's share of the gate subset ----
#pragma unroll
    for (int t = 0; t < GITR; ++t) {
        float4 p0 = psb[gbase + t * 512];
        float4 p1 = psb[gbase + t * 512 + 1];
        v2f px = { p0.x, p1.x }, py = { p0.y, p1.y };
        v2f pz = { p0.z, p1.z }, pw = { p0.w, p1.w };
#pragma unroll
        for (int q = 0; q < 8; ++q) {
            v2f sv = __builtin_elementwise_fma(splat2(qx[q]), px,
                     __builtin_elementwise_fma(splat2(qy[q]), py,
                     __builtin_elementwise_fma(splat2(qz[q]), pz, pw)));
            smax2[q] = __builtin_elementwise_max(smax2[q], sv);
        }
    }
#pragma unroll
    for (int q = 0; q < 8; ++q) smaxs[wv][q][lane] = fmaxf(smax2[q].x, smax2[q].y);
    __syncthreads();

    // ---- gate: combine 4 wave-shares elementwise; each wave sorts 2 q's ----
#pragma unroll
    for (int qq = 0; qq < 2; ++qq) {
        const int q = wv * 2 + qq;
        float v = fmaxf(fmaxf(smaxs[0][q][lane], smaxs[1][q][lane]),
                        fmaxf(smaxs[2][q][lane], smaxs[3][q][lane]));
#pragma unroll
        for (int k = 2; k <= 64; k <<= 1)
#pragma unroll
            for (int j = k >> 1; j >= 1; j >>= 1) {
                float o = __shfl_xor(v, j);
                bool up = ((lane & k) == 0);
                bool keepmin = (((lane & j) == 0) == up);
                v = keepmin ? fminf(v, o) : fmaxf(v, o);
            }
        float m = __shfl(v, 44);          // provable LB on subset 20th-best
        if (lane == 0) gates[q] = m - 1e-4f - 1e-5f * fabsf(m);
    }
    __syncthreads();
    float sgate[8];
#pragma unroll
    for (int q = 0; q < 8; ++q) sgate[q] = gates[q];

    // ---- pass 2: gated append into the SHARED per-query queues ----
#pragma unroll
    for (int t = 0; t < WITR; ++t) {
        const int jb = lbase + t * 512;
        float4 p0 = psb[jb];
        float4 p1 = psb[jb + 1];
        v2f px = { p0.x, p1.x }, py = { p0.y, p1.y };
        v2f pz = { p0.z, p1.z }, pw = { p0.w, p1.w };
#pragma unroll
        for (int q = 0; q < 8; ++q) {
            v2f sv = __builtin_elementwise_fma(splat2(qx[q]), px,
                     __builtin_elementwise_fma(splat2(qy[q]), py,
                     __builtin_elementwise_fma(splat2(qz[q]), pz, pw)));
            if (fmaxf(sv.x, sv.y) >= sgate[q]) {     // common case: wave skips
#pragma unroll
                for (int h = 0; h < 2; ++h) {
                    float svh = h ? sv.y : sv.x;
                    if (svh >= sgate[q]) {
                        int slot = atomicAdd(&qcnt[q], 1);
                        if (slot < FQC)
                            queue[q][slot] = packkey(svh, six[jb + h], jb + h);
                    }
                }
            }
        }
    }
    __syncthreads();

    // ---- analytic window bounds from bin edges ----
    float xLe = (s == 0) ? -3.0e38f
                         : (BIN_LO + (float)(bob[s] + 1) * BIN_W);        // e_hi(bin at s)
    float xRe = (s == NPTS - WINW) ? 3.0e38f
                         : (BIN_LO + (float)bob[s + WINW] * BIN_W);       // e_lo(bin at s+WINW)

    // ---- final: sort each query's shared queue, emit, verify ----
#pragma unroll
    for (int qq = 0; qq < 2; ++qq) {
        const int q = wv * 2 + qq;
        const int cr = qcnt[q];
        const bool ovf = (cr > FQC);
        const int c = cr < FQC ? cr : FQC;
        unsigned long long key = (lane < c) ? queue[q][lane] : 0ull;
#pragma unroll
        for (int k = 2; k <= 64; k <<= 1)
#pragma unroll
            for (int j = k >> 1; j >= 1; j >>= 1) {
                unsigned long long o = __shfl_xor(key, j);
                bool up = ((lane & k) == 0);
                bool keepmax = (((lane & j) == 0) == up);
                bool omax = o > key;
                key = (keepmax == omax) ? o : key;
            }
        if (lane < KNN)
            idx_out[(b * KNN + lane) * NPTS + (q0s + q)] =   // [b][k][n] sorted col
                (int)(unsigned)(key & 0x1FFFu);              // SORTED slot

        // verify: queue complete AND true 20-NN cannot live outside window
        unsigned long long k19 = __shfl(key, 19);
        float s20 = fdec((unsigned)(k19 >> 32));
        float d20 = fmaxf(q2[q] - 2.0f * s20, 0.0f);    // d20^2
        float mg  = 1e-3f + 1e-3f * d20;
        float dL  = qx[q] - xLe;
        float dR  = xRe - qx[q];
        bool ok = !ovf && (c >= KNN) && dL > 0.0f && dR > 0.0f
                  && (d20 + mg < dL * dL) && (d20 + mg < dR * dR);
        if (!ok && lane == 0) {
            unsigned fs = atomicAdd(&fcnt[b], 1u);
            if (fs < 8192u) flist[b * 8192 + fs] = q0s + q;  // sorted slot
        }
    }
}

// ---------------------------------------------------------------------------
// K1b: exact full-scan fallback, 2 queries per block-task, SHARED cap-64
// queue per query (cluster-proof — R2 lesson). grid: 4096 x 256.
// ---------------------------------------------------------------------------
__global__ __launch_bounds__(256, 8) void knn_fb_kernel(const float4* __restrict__ psort,
                                                        const int* __restrict__ sidx,
                                                        int* __restrict__ idx_out,
                                                        const unsigned* __restrict__ fcnt,
                                                        const int* __restrict__ flist)
{
    __shared__ unsigned long long queue[2][FQC];   // per-QUERY shared queues, 1 KB
    __shared__ float smaxs[4][2][64];
    __shared__ float gates[2];
    __shared__ int qcnt[2];

    const int tid  = threadIdx.x;
    const int lane = tid & 63;
    const int wv   = tid >> 6;
    const int bb   = blockIdx.x & 3;
    unsigned cnt = fcnt[bb];
    if (cnt > 8192u) cnt = 8192u;
    if (cnt == 0u) return;
    const float4* pb = psort + bb * NPTS;
    const int* six = sidx + bb * NPTS;
    const int* fl = flist + bb * 8192;
    const int cbase = wv * (NPTS / 4);
    const int tstep = gridDim.x >> 2;

    for (int task = blockIdx.x >> 2; task * 2 < (int)cnt; task += tstep) {
        int qs[2];
        float qx[2], qy[2], qz[2];
        v2f smax2[2];
        if (tid < 2) qcnt[tid] = 0;
#pragma unroll
        for (int q = 0; q < 2; ++q) {
            int e = task * 2 + q;
            if (e >= (int)cnt) e = (int)cnt - 1;      // pad with dup (benign)
            qs[q] = __builtin_amdgcn_readfirstlane(fl[e]);
            float4 qp = pb[qs[q]];
            qx[q] = rfl(qp.x); qy[q] = rfl(qp.y); qz[q] = rfl(qp.z);
            smax2[q] = splat2(-INFINITY);
        }

#pragma unroll 4
        for (int t = 0; t < NPTS / 4 / 128; ++t) {
            float4 p0 = pb[cbase + t * 128 + 2 * lane];
            float4 p1 = pb[cbase + t * 128 + 2 * lane + 1];
            v2f px = { p0.x, p1.x }, py = { p0.y, p1.y };
            v2f pz = { p0.z, p1.z }, pw = { p0.w, p1.w };
#pragma unroll
            for (int q = 0; q < 2; ++q) {
                v2f sv = __builtin_elementwise_fma(splat2(qx[q]), px,
                         __builtin_elementwise_fma(splat2(qy[q]), py,
                         __builtin_elementwise_fma(splat2(qz[q]), pz, pw)));
                smax2[q] = __builtin_elementwise_max(smax2[q], sv);
            }
        }
#pragma unroll
        for (int q = 0; q < 2; ++q) smaxs[wv][q][lane] = fmaxf(smax2[q].x, smax2[q].y);
        __syncthreads();

        if (wv < 2) {
            const int q = wv;
            float v = fmaxf(fmaxf(smaxs[0][q][lane], smaxs[1][q][lane]),
                            fmaxf(smaxs[2][q][lane], smaxs[3][q][lane]));
#pragma unroll
            for (int k = 2; k <= 64; k <<= 1)
#pragma unroll
                for (int j = k >> 1; j >= 1; j >>= 1) {
                    float o = __shfl_xor(v, j);
                    bool up = ((lane & k) == 0);
                    bool keepmin = (((lane & j) == 0) == up);
                    v = keepmin ? fminf(v, o) : fmaxf(v, o);
                }
            float m = __shfl(v, 44);
            if (lane == 0) gates[q] = m - 1e-4f - 1e-5f * fabsf(m);
        }
        __syncthreads();
        float sg0 = gates[0], sg1 = gates[1];

        for (int t = 0; t < NPTS / 4 / 128; ++t) {
            const int jb = cbase + t * 128 + 2 * lane;
            float4 p0 = pb[jb];
            float4 p1 = pb[jb + 1];
            v2f px = { p0.x, p1.x }, py = { p0.y, p1.y };
            v2f pz = { p0.z, p1.z }, pw = { p0.w, p1.w };
#pragma unroll
            for (int q = 0; q < 2; ++q) {
                float sg = q ? sg1 : sg0;
                v2f sv = __builtin_elementwise_fma(splat2(qx[q]), px,
                         __builtin_elementwise_fma(splat2(qy[q]), py,
                         __builtin_elementwise_fma(splat2(qz[q]), pz, pw)));
                if (fmaxf(sv.x, sv.y) >= sg) {
#pragma unroll
                    for (int h = 0; h < 2; ++h) {
                        float svh = h ? sv.y : sv.x;
                        if (svh >= sg) {
                            int slot = atomicAdd(&qcnt[q], 1);
                            if (slot < FQC)
                                queue[q][slot] = packkey(svh, six[jb + h], jb + h);
                        }
                    }
                }
            }
        }
        __syncthreads();

        if (wv < 2) {
            const int q = wv;
            int c = qcnt[q]; c = c < FQC ? c : FQC;
            unsigned long long key = (lane < c) ? queue[q][lane] : 0ull;
#pragma unroll
            for (int k = 2; k <= 64; k <<= 1)
#pragma unroll
                for (int j = k >> 1; j >= 1; j >>= 1) {
                    unsigned long long o = __shfl_xor(key, j);
                    bool up = ((lane & k) == 0);
                    bool keepmax = (((lane & j) == 0) == up);
                    bool omax = o > key;
                    key = (keepmax == omax) ? o : key;
                }
            if (lane < KNN)
                idx_out[(bb * KNN + lane) * NPTS + qs[q]] =
                    (int)(unsigned)(key & 0x1FFFu);
        }
        __syncthreads();   // protect LDS reuse by next task
    }
}

// ---------------------------------------------------------------------------
// K2: x0 moments (6 sums + 21 upper-tri products) — SORTED domain. Plain
// (no fences — R6 lesson: per-block agent-scope fence = L2 writeback).
// ---------------------------------------------------------------------------
__global__ __launch_bounds__(256) void moments_x_kernel(const float4* __restrict__ psort,
                                                        const int* __restrict__ idx,
                                                        float* __restrict__ sums1p)
{
    const int b  = blockIdx.x / 80;
    const int r0 = (blockIdx.x - b * 80) * 2048;
    const float4* pb = psort + b * NPTS;
    const int* ib = idx + b * NKTOT;

    float v[27];
#pragma unroll
    for (int i = 0; i < 27; ++i) v[i] = 0.f;

    for (int e = 0; e < 8; ++e) {
        const int id = r0 + e * 256 + threadIdx.x;   // [k][n] linear, coalesced
        const int n = id & (NPTS - 1);
        const int j = ib[id];
        float4 c4 = pb[n];
        float4 e4 = pb[j];
        float x[6] = { c4.x, c4.y, c4.z, e4.x - c4.x, e4.y - c4.y, e4.z - c4.z };
        int p = 6;
#pragma unroll
        for (int d = 0; d < 6; ++d) {
            v[d] += x[d];
#pragma unroll
            for (int ee = d; ee < 6; ++ee) v[p++] += x[d] * x[ee];
        }
    }
#pragma unroll
    for (int i = 0; i < 27; ++i)
        for (int o = 32; o > 0; o >>= 1) v[i] += __shfl_xor(v[i], o);

    __shared__ float red[4][27];
    const int lane = threadIdx.x & 63, w = threadIdx.x >> 6;
    if (lane == 0)
#pragma unroll
        for (int i = 0; i < 27; ++i) red[w][i] = v[i];
    __syncthreads();
    if (threadIdx.x < 27) {
        float acc = red[0][threadIdx.x] + red[1][threadIdx.x] + red[2][threadIdx.x] + red[3][threadIdx.x];
        int slot = blockIdx.x & 63;
        atomicAdd(&sums1p[(slot * BATCH + b) * 27 + threadIdx.x], acc);
    }
}

// ---------------------------------------------------------------------------
// K3: finalize GN1 stats -> folded per-channel weights w1f[b][c][8].
// ---------------------------------------------------------------------------
__global__ void finalize1_kernel(const float* __restrict__ sums1p,
                                 const float* __restrict__ w1, const float* __restrict__ b1,
                                 const float* __restrict__ g1, const float* __restrict__ beta1,
                                 float* __restrict__ w1f)
{
    __shared__ float S[BATCH][27];
    const int t = threadIdx.x;
    if (t < 108) {
        int b = t / 27, i = t % 27;
        float acc = 0.f;
        for (int s = 0; s < 64; ++s) acc += sums1p[(s * BATCH + b) * 27 + i];
        S[b][i] = acc;
    }
    __syncthreads();
    const int b = t >> 5, c = t & 31;
    const float invS = 1.0f / (float)NKTOT;
    float Ex[6], M[6][6];
#pragma unroll
    for (int d = 0; d < 6; ++d) Ex[d] = S[b][d] * invS;
    int p = 6;
#pragma unroll
    for (int d = 0; d < 6; ++d)
#pragma unroll
        for (int e = d; e < 6; ++e) { float v = S[b][p++] * invS; M[d][e] = v; M[e][d] = v; }
    const int g = c >> 2;
    float msum = 0.f, qsum = 0.f;
    for (int cc = g * 4; cc < g * 4 + 4; ++cc) {
        float w[6];
#pragma unroll
        for (int d = 0; d < 6; ++d) w[d] = w1[cc * 6 + d];
        float dotEx = 0.f;
#pragma unroll
        for (int d = 0; d < 6; ++d) dotEx += w[d] * Ex[d];
        float Ey = dotEx + b1[cc];
        float Ey2 = 0.f;
#pragma unroll
        for (int d = 0; d < 6; ++d)
#pragma unroll
            for (int e = 0; e < 6; ++e) Ey2 += w[d] * w[e] * M[d][e];
        Ey2 += 2.0f * b1[cc] * dotEx + b1[cc] * b1[cc];
        msum += Ey; qsum += Ey2;
    }
    float m = msum * 0.25f;
    float var = qsum * 0.25f - m * m;
    float inv = rsqrtf(var + EPS);
    float s = g1[c] * inv;
    float tt = s * (b1[c] - m) + beta1[c];
    float* o = w1f + (b * 32 + c) * 8;
#pragma unroll
    for (int d = 0; d < 6; ++d) o[d] = s * w1[c * 6 + d];
    o[6] = tt; o[7] = 0.f;
}

// ---------------------------------------------------------------------------
// K4: fused main pass (SORTED domain). Plain (no epilogue/fence).
// ---------------------------------------------------------------------------
__global__ __launch_bounds__(256, 3) void fused_main_kernel(
    const float4* __restrict__ psort, const int* __restrict__ idxb,
    const float* __restrict__ w1f, const float* __restrict__ w2, const float* __restrict__ b2,
    float* __restrict__ sums2p, unsigned int* __restrict__ maxenc, unsigned int* __restrict__ minenc)
{
    __shared__ __align__(16) float w2t[32 * 64];    // W2^T: [k][c]   8 KB
    __shared__ __align__(16) float z1s[32 * 256];   // z1:   [k][n]  32 KB
    __shared__ __align__(16) float4 w1s4[64];       // folded W1 [32][8]
    __shared__ float b2s[64];
    __shared__ float redmx[256], redmn[256], sqred[64];

    const int t   = threadIdx.x;
    const int blk = blockIdx.x;
    const int nc  = blk & 15;
    const int k   = (blk >> 4) % 20;
    const int b   = blk / 320;          // 320 blocks per batch (16 nc * 20 k)

    for (int i = t; i < 512; i += 256) {
        float4 v = ((const float4*)w2)[i];
        int c = i >> 3, kq = (i & 7) * 4;
        w2t[(kq + 0) * 64 + c] = v.x; w2t[(kq + 1) * 64 + c] = v.y;
        w2t[(kq + 2) * 64 + c] = v.z; w2t[(kq + 3) * 64 + c] = v.w;
    }
    if (t < 64) { w1s4[t] = ((const float4*)w1f)[b * 64 + t]; b2s[t] = b2[t]; }

    const int wvi = t >> 6;
    const int cg8 = t & 7;            // channel octet == GN group (GEMM)
    const int n0  = (t >> 3) * 8;     // n-group base 0..248 (GEMM)
    const int c0  = cg8 * 8;
    const float4* pb = psort + b * NPTS;
    const int nbase = nc * 512;
    const int* idxrow = idxb + (b * KNN + k) * NPTS;   // [b][k][n]: coalesced

    float mx[8], mn[8];
#pragma unroll
    for (int ci = 0; ci < 8; ++ci) { mx[ci] = -INFINITY; mn[ci] = INFINITY; }
    float gs = 0.f, gq = 0.f;

    for (int ph = 0; ph < 2; ++ph) {
        // ---- fill z1[32][256]: thread owns n = nbase+ph*256+t, all 32 ch ----
        const int n = nbase + ph * 256 + t;
        const int j = idxrow[n];
        float4 c4 = pb[n];
        float4 e4 = pb[j];
        float x0[6] = { c4.x, c4.y, c4.z, e4.x - c4.x, e4.y - c4.y, e4.z - c4.z };

        __syncthreads();   // staging done (ph=0) / previous GEMM reads done
#pragma unroll
        for (int c = 0; c < 32; ++c) {
            float4 wA = w1s4[c * 2 + 0];
            float4 wB = w1s4[c * 2 + 1];
            float z = wB.z;
            z = fmaf(wA.x, x0[0], z); z = fmaf(wA.y, x0[1], z); z = fmaf(wA.z, x0[2], z);
            z = fmaf(wA.w, x0[3], z); z = fmaf(wB.x, x0[4], z); z = fmaf(wB.y, x0[5], z);
            z1s[c * 256 + t] = eluf(z);
        }
        __syncthreads();

        // ---- GEMM: 8c x 8n per thread, 4 b128 per 64 FMA ----
        float acc[8][8];
#pragma unroll
        for (int ci = 0; ci < 8; ++ci) {
            float bb = b2s[c0 + ci];
#pragma unroll
            for (int pj = 0; pj < 8; ++pj) acc[ci][pj] = bb;
        }
#pragma unroll
        for (int kk = 0; kk < 32; ++kk) {
            float4 a0 = *(const float4*)&w2t[kk * 64 + c0];
            float4 a1 = *(const float4*)&w2t[kk * 64 + c0 + 4];
            float4 z0 = *(const float4*)&z1s[kk * 256 + n0];
            float4 z1v = *(const float4*)&z1s[kk * 256 + n0 + 4];
            float avv[8] = { a0.x, a0.y, a0.z, a0.w, a1.x, a1.y, a1.z, a1.w };
            float zvv[8] = { z0.x, z0.y, z0.z, z0.w, z1v.x, z1v.y, z1v.z, z1v.w };
#pragma unroll
            for (int ci = 0; ci < 8; ++ci)
#pragma unroll
                for (int pj = 0; pj < 8; ++pj) acc[ci][pj] = fmaf(avv[ci], zvv[pj], acc[ci][pj]);
        }
#pragma unroll
        for (int ci = 0; ci < 8; ++ci)
#pragma unroll
            for (int pj = 0; pj < 8; ++pj) {
                float v = acc[ci][pj];
                gs += v; gq = fmaf(v, v, gq);
                mx[ci] = fmaxf(mx[ci], v); mn[ci] = fminf(mn[ci], v);
            }
    }

    // reduce over the 8 n-groups within this wave (lane bits 3,4,5)
#pragma unroll
    for (int m = 8; m <= 32; m <<= 1) {
#pragma unroll
        for (int ci = 0; ci < 8; ++ci) {
            mx[ci] = fmaxf(mx[ci], __shfl_xor(mx[ci], m));
            mn[ci] = fminf(mn[ci], __shfl_xor(mn[ci], m));
        }
        gs += __shfl_xor(gs, m);
        gq += __shfl_xor(gq, m);
    }
    if ((t & 63) < 8) {
        const int l = t & 7;
#pragma unroll
        for (int ci = 0; ci < 8; ++ci) {
            redmx[wvi * 64 + l * 8 + ci] = mx[ci];
            redmn[wvi * 64 + l * 8 + ci] = mn[ci];
        }
        sqred[(wvi * 8 + l) * 2 + 0] = gs;
        sqred[(wvi * 8 + l) * 2 + 1] = gq;
    }
    __syncthreads();
    if (t < 64) {
        float m = fmaxf(fmaxf(redmx[t], redmx[64 + t]), fmaxf(redmx[128 + t], redmx[192 + t]));
        atomicMax(&maxenc[(b * 64 + t) * KNN + k], fenc(m));
    } else if (t < 128) {
        int c = t - 64;
        float m = fminf(fminf(redmn[c], redmn[64 + c]), fminf(redmn[128 + c], redmn[192 + c]));
        atomicMin(&minenc[(b * 64 + c) * KNN + k], fenc(m));
    } else if (t < 144) {
        int i2 = t - 128, g = i2 >> 1, w = i2 & 1;
        float v = 0.f;
#pragma unroll
        for (int wv2 = 0; wv2 < 4; ++wv2)
            v += sqred[(wv2 * 8 + g) * 2 + w];
        int slot = blk & 63;
        atomicAdd(&sums2p[((slot * BATCH + b) * 8 + g) * 2 + w], v);
    }
}

// ---------------------------------------------------------------------------
// K5: build m1[b,c,k] = ELU(GN2-affine applied to max-or-min over n of y2)
// ---------------------------------------------------------------------------
__global__ void build_m1_kernel(const float* __restrict__ sums2p,
                                const unsigned int* __restrict__ maxenc,
                                const unsigned int* __restrict__ minenc,
                                const float* __restrict__ gamma, const float* __restrict__ beta,
                                float* __restrict__ m1)
{
    const int t = blockIdx.x * 256 + threadIdx.x;   // (b*64+c)*20+k
    const int b = t / 1280;
    const int r = t - b * 1280;
    const int c = r / 20;
    const int g = c >> 3;
    float s = 0.f, q = 0.f;
    for (int sl = 0; sl < 64; ++sl) {
        s += sums2p[((sl * BATCH + b) * 8 + g) * 2 + 0];
        q += sums2p[((sl * BATCH + b) * 8 + g) * 2 + 1];
    }
    const float cnt = 8.0f * (float)NKTOT;
    float m = s / cnt;
    float var = q / cnt - m * m;
    float inv = rsqrtf(var + EPS);
    float sc = gamma[c] * inv;
    float tt = beta[c] - sc * m;
    float y = (sc >= 0.f) ? fdec(maxenc[t]) : fdec(minenc[t]);
    m1[t] = elu(sc * y + tt);
}

// ---------------------------------------------------------------------------
// K6/K8: pointwise conv (CIN -> COUT over K=20) + raw output + GN stat partials
// ---------------------------------------------------------------------------
template <int CIN, int SLOTS>
__global__ void p2_gemm_kernel(const float* __restrict__ zin, const float* __restrict__ w,
                               const float* __restrict__ bias, float* __restrict__ yout,
                               float* __restrict__ sumsp, int chans_per_group)
{
    const int t = blockIdx.x * 256 + threadIdx.x;
    const int per_b = (gridDim.x * 256) / BATCH;
    const int b = t / per_b;
    const int r = t - b * per_b;
    const int o = r / 20;
    const int k = r - o * 20;
    const float* zb = zin + b * CIN * 20;
    const float* wrow = w + o * CIN;
    float acc = bias[o];
    for (int c = 0; c < CIN; c += 4) {
        float4 wv = *(const float4*)&wrow[c];
        acc += wv.x * zb[(c + 0) * 20 + k] + wv.y * zb[(c + 1) * 20 + k]
             + wv.z * zb[(c + 2) * 20 + k] + wv.w * zb[(c + 3) * 20 + k];
    }
    yout[t] = acc;

    __shared__ float ls[16];
    if (threadIdx.x < 16) ls[threadIdx.x] = 0.f;
    __syncthreads();
    const int g = o / chans_per_group;
    atomicAdd(&ls[g * 2 + 0], acc);
    atomicAdd(&ls[g * 2 + 1], acc * acc);
    __syncthreads();
    if (threadIdx.x < 16) {
        int slot = blockIdx.x & (SLOTS - 1);
        atomicAdd(&sumsp[(slot * BATCH + b) * 16 + threadIdx.x], ls[threadIdx.x]);
    }
}

// K7/K9: apply GN affine + ELU using partial sums
template <int SLOTS>
__global__ void p2_finalize_kernel(const float* __restrict__ y, const float* __restrict__ sumsp,
                                   const float* __restrict__ gamma, const float* __restrict__ beta,
                                   float* __restrict__ z, int chans_per_group, float cnt)
{
    const int t = blockIdx.x * 256 + threadIdx.x;
    const int per_b = (gridDim.x * 256) / BATCH;
    const int b = t / per_b;
    const int r = t - b * per_b;
    const int o = r / 20;
    const int g = o / chans_per_group;
    float s = 0.f, q = 0.f;
    for (int sl = 0; sl < SLOTS; ++sl) {
        s += sumsp[(sl * BATCH + b) * 16 + g * 2 + 0];
        q += sumsp[(sl * BATCH + b) * 16 + g * 2 + 1];
    }
    float m = s / cnt;
    float var = q / cnt - m * m;
    float inv = rsqrtf(var + EPS);
    float v = gamma[o] * inv * (y[t] - m) + beta[o];
    z[t] = elu(v);
}

// ---------------------------------------------------------------------------
extern "C" void kernel_launch(void* const* d_in, const int* in_sizes, int n_in,
                              void* d_out, int out_size, void* d_ws, size_t ws_size,
                              hipStream_t stream)
{
    const float* points  = (const float*)d_in[0];
    const float* p1_w0   = (const float*)d_in[1];
    const float* p1_b0   = (const float*)d_in[2];
    const float* p1_g0   = (const float*)d_in[3];
    const float* p1_bt0  = (const float*)d_in[4];
    const float* p1_w1   = (const float*)d_in[5];
    const float* p1_b1   = (const float*)d_in[6];
    const float* p1_g1   = (const float*)d_in[7];
    const float* p1_bt1  = (const float*)d_in[8];
    const float* p2_w0   = (const float*)d_in[9];
    const float* p2_b0   = (const float*)d_in[10];
    const float* p2_g0   = (const float*)d_in[11];
    const float* p2_bt0  = (const float*)d_in[12];
    const float* p2_w1   = (const float*)d_in[13];
    const float* p2_b1   = (const float*)d_in[14];
    const float* p2_g1   = (const float*)d_in[15];
    const float* p2_bt1  = (const float*)d_in[16];
    float* out = (float*)d_out;

    float* ws = (float*)d_ws;
    int*      idx     = (int*)ws;                    // 655360  ([b][k][n], sorted cols)
    float*    sums1p  = ws + 655360;                 // 6912   (zeroed by prep)
    float*    sums2p  = sums1p + 6912;               // 4096   (zeroed by prep)
    float*    sumsAp  = sums2p + 4096;               // 1024   (zeroed by prep)
    float*    sumsBp  = sumsAp + 1024;               // 1024   (zeroed by prep)
    unsigned* maxenc  = (unsigned*)(sumsBp + 1024);  // 5120   (zeroed by prep)
    unsigned* minenc  = maxenc + 5120;               // 5120   (0xFF by prep)
    float*    w1f     = (float*)(minenc + 5120);     // 1024
    float*    m1      = w1f + 1024;                  // 5120
    float*    yp2a    = m1 + 5120;                   // 40960
    float*    zp2a    = yp2a + 40960;                // 40960
    float*    yp2b    = zp2a + 40960;                // 81920
    // pts4 (original order) aliases yp2a onward; live only until scatter.
    float4*   pts4    = (float4*)yp2a;
    // hist partials alias the idx region (consumed by scatter BEFORE knn writes idx)
    int*      Pcur_part = idx;                       // 131072 ints, transient
    // sorted-domain arrays (fresh space after yp2b; psort lives through fused_main)
    float*    psortf  = yp2b + 81920;                // 131072 (float4[4][8192])
    float4*   psort4  = (float4*)psortf;
    int*      sidx    = (int*)(psortf + 131072);     // 32768
    int*      binof   = sidx + 32768;                // 32768 (+64 pad)
    unsigned* fcnt8   = (unsigned*)(binof + 32768 + 64); // 8 (+56 pad)
    int*      flist   = (int*)(fcnt8 + 64);          // 32768 (4 x 8192 per-batch lists)

    // zero region = sums1p..maxenc contiguous: 6912+4096+1024+1024+5120 = 18176
    prep_kernel<<<128, 256, 0, stream>>>(points, pts4, sums1p, minenc, fcnt8, Pcur_part);
    scatter_kernel<<<128, 256, 0, stream>>>(pts4, Pcur_part, psort4, sidx, binof);
    knn_win_kernel<<<4096, 256, 0, stream>>>(psort4, sidx, binof, idx, fcnt8, flist);
    knn_fb_kernel<<<4096, 256, 0, stream>>>(psort4, sidx, idx, fcnt8, flist);
    moments_x_kernel<<<320, 256, 0, stream>>>(psort4, idx, sums1p);
    finalize1_kernel<<<1, 128, 0, stream>>>(sums1p, p1_w0, p1_b0, p1_g0, p1_bt0, w1f);
    // grid MUST be 1280 = 4 b * 20 k * 16 nc  (b = blk/320; larger grids give
    // b >= BATCH -> OOB idx reads -> memory fault, see R4 crash)
    fused_main_kernel<<<1280, 256, 0, stream>>>(psort4, idx, w1f, p1_w1, p1_b1,
                                                sums2p, maxenc, minenc);
    build_m1_kernel<<<20, 256, 0, stream>>>(sums2p, maxenc, minenc, p1_g1, p1_bt1, m1);
    p2_gemm_kernel<64, 16><<<160, 256, 0, stream>>>(m1, p2_w0, p2_b0, yp2a, sumsAp, 64);
    p2_finalize_kernel<16><<<160, 256, 0, stream>>>(yp2a, sumsAp, p2_g0, p2_bt0, zp2a, 64, 1280.0f);
    p2_gemm_kernel<512, 16><<<320, 256, 0, stream>>>(zp2a, p2_w1, p2_b1, yp2b, sumsBp, 128);
    p2_finalize_kernel<16><<<320, 256, 0, stream>>>(yp2b, sumsBp, p2_g1, p2_bt1, out, 128, 2560.0f);
}